// Round 1
// baseline (2834.048 us; speedup 1.0000x reference)
//
#include <hip/hip_runtime.h>
#include <math.h>

// Problem constants
// B=4, H=W=64 -> L=4096, DIM=128, D_INNER=256, D_STATE=16, D_CONV=4, DT_RANK=8, NSLICES=16
#define LSEQ 4096

// Workspace layout (floats). Total = 35,127,296 floats = 140,509,184 bytes (~134 MB)
#define XZ_OFF   0ULL
#define XZ_SZ    (4ULL * 512 * 4096)        // 8,388,608  : xz[b][p][l], l-contiguous
#define U_OFF    (XZ_OFF + XZ_SZ)
#define DIR_SZ   (4ULL * 256 * 4096)        // 4,194,304 per direction
#define DELTA_OFF (U_OFF + 3ULL * DIR_SZ)   // delta, overwritten in-place by scan output y
#define BC_OFF   (DELTA_OFF + 3ULL * DIR_SZ)
#define BC_SZ    (4ULL * 4096 * 32)         // BC[b][l][0..15]=B, [16..31]=C

__device__ __forceinline__ float sigmoidf_(float x) { return 1.0f / (1.0f + __expf(-x)); }
__device__ __forceinline__ float siluf_(float x)    { return x * sigmoidf_(x); }
__device__ __forceinline__ float softplusf_(float x){ return (x > 20.0f) ? x : log1pf(__expf(x)); }

// dir permutation: scan-domain index j -> original-domain index
__device__ __forceinline__ int perm_idx(int dir, int j) {
    if (dir == 0) return j;
    if (dir == 1) return 4095 - j;
    return ((j & 15) << 8) | (j >> 4);   // slice: j = jj*16+s -> s*256+jj
}

// ---------------------------------------------------------------------------
// K1: xz[b][p][l] = sum_c in_proj_w[p][c] * x_in[b][l][c]
// grid(128, 4), block 256. LDS-tiled: 32 l x 128 c.
__global__ void inproj_kernel(const float* __restrict__ x,
                              const float* __restrict__ w,
                              float* __restrict__ xz) {
    const int b = blockIdx.y;
    const int l0 = blockIdx.x * 32;
    __shared__ float xs[32 * 132];  // pad 128->132 (16B-aligned rows, breaks bank conflicts)
    for (int idx = threadIdx.x; idx < 32 * 128; idx += 256) {
        int li = idx >> 7, c = idx & 127;
        xs[li * 132 + c] = x[((size_t)(b * 4096 + l0 + li)) * 128 + c];
    }
    __syncthreads();
    for (int o = threadIdx.x; o < 512 * 32; o += 256) {
        int p = o >> 5, li = o & 31;
        const float* wr = w + p * 128;
        const float* xr = xs + li * 132;
        float acc = 0.0f;
        #pragma unroll
        for (int c = 0; c < 128; c += 4) {
            float4 wv = *(const float4*)(wr + c);
            float4 xv = *(const float4*)(xr + c);
            acc += wv.x * xv.x + wv.y * xv.y + wv.z * xv.z + wv.w * xv.w;
        }
        xz[((size_t)(b * 512 + p)) * 4096 + l0 + li] = acc;
    }
}

// ---------------------------------------------------------------------------
// K2: u_dir[b][d][l] = silu(conv_b[d] + sum_k conv_w[d][k] * x_dir[b][d][l-3+k])
// x_dir[j] = xz[b][d][perm(j)].  grid(256, 4, 3), block 256, 16 l per thread.
__global__ void conv_silu_kernel(const float* __restrict__ ws_xz,
                                 float* __restrict__ ws_u,
                                 const float* __restrict__ cw0, const float* __restrict__ cb0,
                                 const float* __restrict__ cw1, const float* __restrict__ cb1,
                                 const float* __restrict__ cw2, const float* __restrict__ cb2) {
    const int d = blockIdx.x, b = blockIdx.y, dir = blockIdx.z;
    const float* cw = (dir == 0) ? cw0 : (dir == 1) ? cw1 : cw2;
    const float* cb = (dir == 0) ? cb0 : (dir == 1) ? cb1 : cb2;
    const float* xrow = ws_xz + ((size_t)(b * 512 + d)) * 4096;
    float* urow = ws_u + (size_t)dir * DIR_SZ + ((size_t)(b * 256 + d)) * 4096;
    const float w0 = cw[d * 4 + 0], w1 = cw[d * 4 + 1], w2 = cw[d * 4 + 2], w3 = cw[d * 4 + 3];
    const float bb = cb[d];
    for (int i = 0; i < 16; ++i) {
        int l = threadIdx.x + i * 256;
        float acc = bb;
        #pragma unroll
        for (int k = 0; k < 4; ++k) {
            int j = l - 3 + k;
            if (j >= 0) {
                float wv = (k == 0) ? w0 : (k == 1) ? w1 : (k == 2) ? w2 : w3;
                acc += wv * xrow[perm_idx(dir, j)];
            }
        }
        urow[l] = siluf_(acc);
    }
}

// ---------------------------------------------------------------------------
// K3: x_dbl = x_proj_w(40x256) @ u-tile; rows 0..7 -> delta via dt_proj+softplus;
// rows 8..39 -> BC[b][l][32].  grid(128, 4, 3), block 256.
__global__ void xdbl_kernel(float* __restrict__ ws,
                            const float* __restrict__ xw0, const float* __restrict__ xw1, const float* __restrict__ xw2,
                            const float* __restrict__ dw0, const float* __restrict__ dw1, const float* __restrict__ dw2,
                            const float* __restrict__ db0, const float* __restrict__ db1, const float* __restrict__ db2) {
    const int l0 = blockIdx.x * 32, b = blockIdx.y, dir = blockIdx.z;
    const float* xw = (dir == 0) ? xw0 : (dir == 1) ? xw1 : xw2;
    const float* dw = (dir == 0) ? dw0 : (dir == 1) ? dw1 : dw2;
    const float* db = (dir == 0) ? db0 : (dir == 1) ? db1 : db2;
    const float* u = ws + U_OFF + (size_t)dir * DIR_SZ;
    float* deltab  = ws + DELTA_OFF + (size_t)dir * DIR_SZ;
    float* bc      = ws + BC_OFF + (size_t)dir * BC_SZ;

    __shared__ float ut[256 * 33];
    __shared__ float xd[40 * 33];

    for (int idx = threadIdx.x; idx < 256 * 32; idx += 256) {
        int d = idx >> 5, li = idx & 31;
        ut[d * 33 + li] = u[((size_t)(b * 256 + d)) * 4096 + l0 + li];
    }
    __syncthreads();
    for (int o = threadIdx.x; o < 40 * 32; o += 256) {
        int r = o >> 5, li = o & 31;
        const float* wr = xw + r * 256;
        float acc = 0.0f;
        #pragma unroll 8
        for (int d = 0; d < 256; ++d) acc += wr[d] * ut[d * 33 + li];
        xd[r * 33 + li] = acc;
    }
    __syncthreads();
    // B/C rows 8..39 -> (b, l, 32) layout
    for (int idx = threadIdx.x; idx < 32 * 32; idx += 256) {
        int li = idx >> 5, rr = idx & 31;
        bc[((size_t)(b * 4096 + l0 + li)) * 32 + rr] = xd[(8 + rr) * 33 + li];
    }
    // delta = softplus(dt_w @ dt_raw + dt_b)
    for (int o = threadIdx.x; o < 256 * 32; o += 256) {
        int d = o >> 5, li = o & 31;
        float acc = db[d];
        #pragma unroll
        for (int r = 0; r < 8; ++r) acc += dw[d * 8 + r] * xd[r * 33 + li];
        deltab[((size_t)(b * 256 + d)) * 4096 + l0 + li] = softplusf_(acc);
    }
}

// ---------------------------------------------------------------------------
// K4: selective scan. 16 lanes per (b,d) chain (lane = state n).
// Writes y_scan = (sum_n h*C) + D*u IN PLACE over delta (same idx just read).
// grid(64, 4, 3), block 64 (4 chains/wave).
__global__ void scan_kernel(float* __restrict__ ws,
                            const float* __restrict__ Al0, const float* __restrict__ Dp0,
                            const float* __restrict__ Al1, const float* __restrict__ Dp1,
                            const float* __restrict__ Al2, const float* __restrict__ Dp2) {
    const int dg = blockIdx.x, b = blockIdx.y, dir = blockIdx.z;
    const float* Al = (dir == 0) ? Al0 : (dir == 1) ? Al1 : Al2;
    const float* Dp = (dir == 0) ? Dp0 : (dir == 1) ? Dp1 : Dp2;
    const int chain = threadIdx.x >> 4;
    const int n = threadIdx.x & 15;
    const int d = dg * 4 + chain;
    const float An = -__expf(Al[d * 16 + n]);   // A = -exp(A_log)
    const float Dd = Dp[d];
    const float* urow = ws + U_OFF + (size_t)dir * DIR_SZ + ((size_t)(b * 256 + d)) * 4096;
    float* drow = ws + DELTA_OFF + (size_t)dir * DIR_SZ + ((size_t)(b * 256 + d)) * 4096;
    const float* bcb = ws + BC_OFF + (size_t)dir * BC_SZ + (size_t)b * 4096 * 32;

    float h = 0.0f;
    for (int l = 0; l < 4096; ++l) {
        float dv = drow[l];          // broadcast (all 16 lanes same addr)
        float uv = urow[l];
        float Bn = bcb[l * 32 + n];
        float Cn = bcb[l * 32 + 16 + n];
        h = h * __expf(dv * An) + (dv * uv) * Bn;
        float yp = h * Cn;
        yp += __shfl_xor(yp, 1, 16);
        yp += __shfl_xor(yp, 2, 16);
        yp += __shfl_xor(yp, 4, 16);
        yp += __shfl_xor(yp, 8, 16);
        if (n == 0) drow[l] = yp + Dd * uv;   // overwrite delta[l] after its last read
    }
}

// ---------------------------------------------------------------------------
// K5: y_total[b][d][l0] = silu(z[b][d][l0]) * (yf[l0] + yb[4095-l0] + ys[perm_s^-1(l0)])
// out[b][l0][o] = sum_d out_proj_w[o][d] * y_total.  grid(128, 4), block 256.
__global__ void epilogue_kernel(const float* __restrict__ ws,
                                const float* __restrict__ ow,
                                float* __restrict__ out) {
    const int l0 = blockIdx.x * 32, b = blockIdx.y;
    __shared__ float yt[256 * 33];
    const float* yf = ws + DELTA_OFF;
    const float* yb = ws + DELTA_OFF + DIR_SZ;
    const float* ys = ws + DELTA_OFF + 2 * DIR_SZ;

    for (int idx = threadIdx.x; idx < 256 * 32; idx += 256) {
        int d = idx >> 5, li = idx & 31;
        int l = l0 + li;
        float z  = ws[XZ_OFF + ((size_t)(b * 512 + 256 + d)) * 4096 + l];
        float vf = yf[((size_t)(b * 256 + d)) * 4096 + l];
        float vb = yb[((size_t)(b * 256 + d)) * 4096 + (4095 - l)];
        int s = l >> 8, j = l & 255;
        float vs = ys[((size_t)(b * 256 + d)) * 4096 + (j * 16 + s)];
        yt[d * 33 + li] = (vf + vb + vs) * siluf_(z);
    }
    __syncthreads();

    const int o = threadIdx.x & 127;
    const int li0 = (threadIdx.x >> 7) * 16;
    float acc[16];
    #pragma unroll
    for (int k = 0; k < 16; ++k) acc[k] = 0.0f;
    const float* wr = ow + o * 256;
    for (int d = 0; d < 256; ++d) {
        float wv = wr[d];
        const float* yrow = yt + d * 33 + li0;
        #pragma unroll
        for (int k = 0; k < 16; ++k) acc[k] += wv * yrow[k];
    }
    #pragma unroll
    for (int k = 0; k < 16; ++k)
        out[((size_t)(b * 4096 + l0 + li0 + k)) * 128 + o] = acc[k];
}

// ---------------------------------------------------------------------------
extern "C" void kernel_launch(void* const* d_in, const int* in_sizes, int n_in,
                              void* d_out, int out_size, void* d_ws, size_t ws_size,
                              hipStream_t stream) {
    const float* x_in = (const float*)d_in[0];
    const float* ipw  = (const float*)d_in[1];
    const float* cw[3]  = {(const float*)d_in[2],  (const float*)d_in[9],  (const float*)d_in[16]};
    const float* cb[3]  = {(const float*)d_in[3],  (const float*)d_in[10], (const float*)d_in[17]};
    const float* xpw[3] = {(const float*)d_in[4],  (const float*)d_in[11], (const float*)d_in[18]};
    const float* dtw[3] = {(const float*)d_in[5],  (const float*)d_in[12], (const float*)d_in[19]};
    const float* dtb[3] = {(const float*)d_in[6],  (const float*)d_in[13], (const float*)d_in[20]};
    const float* alog[3]= {(const float*)d_in[7],  (const float*)d_in[14], (const float*)d_in[21]};
    const float* dp[3]  = {(const float*)d_in[8],  (const float*)d_in[15], (const float*)d_in[22]};
    const float* ow   = (const float*)d_in[23];
    float* ws  = (float*)d_ws;
    float* out = (float*)d_out;

    inproj_kernel<<<dim3(128, 4), 256, 0, stream>>>(x_in, ipw, ws);
    conv_silu_kernel<<<dim3(256, 4, 3), 256, 0, stream>>>(ws, ws + U_OFF,
        cw[0], cb[0], cw[1], cb[1], cw[2], cb[2]);
    xdbl_kernel<<<dim3(128, 4, 3), 256, 0, stream>>>(ws,
        xpw[0], xpw[1], xpw[2], dtw[0], dtw[1], dtw[2], dtb[0], dtb[1], dtb[2]);
    scan_kernel<<<dim3(64, 4, 3), 64, 0, stream>>>(ws,
        alog[0], dp[0], alog[1], dp[1], alog[2], dp[2]);
    epilogue_kernel<<<dim3(128, 4), 256, 0, stream>>>(ws, ow, out);
}

// Round 2
// 609.533 us; speedup vs baseline: 4.6495x; 4.6495x over previous
//
#include <hip/hip_runtime.h>
#include <math.h>

// Problem constants
// B=4, H=W=64 -> L=4096, DIM=128, D_INNER=256, D_STATE=16, D_CONV=4, DT_RANK=8, NSLICES=16
#define LSEQ 4096

// Workspace layout (floats).
#define XZ_OFF   0ULL
#define XZ_SZ    (4ULL * 512 * 4096)        // xz[b][p][l], l-contiguous
#define U_OFF    (XZ_OFF + XZ_SZ)
#define DIR_SZ   (4ULL * 256 * 4096)        // per direction
#define DELTA_OFF (U_OFF + 3ULL * DIR_SZ)   // delta, overwritten in-place by scan output y (orig l-domain)
#define BC_OFF   (DELTA_OFF + 3ULL * DIR_SZ)
#define BC_SZ    (4ULL * 4096 * 32)         // BC[b][l][0..15]=B, [16..31]=C
#define WT_OFF   BC_OFF                     // wT[256][128]; BC is dead after scan, reuse region

__device__ __forceinline__ float sigmoidf_(float x) { return 1.0f / (1.0f + __expf(-x)); }
__device__ __forceinline__ float siluf_(float x)    { return x * sigmoidf_(x); }
__device__ __forceinline__ float softplusf_(float x){ return (x > 20.0f) ? x : log1pf(__expf(x)); }

// dir permutation: scan-domain index j -> original-domain index
__device__ __forceinline__ int perm_idx(int dir, int j) {
    if (dir == 0) return j;
    if (dir == 1) return 4095 - j;
    return ((j & 15) << 8) | (j >> 4);   // slice: j = jj*16+s -> s*256+jj
}

// ---------------------------------------------------------------------------
// K1: xz[b][p][l] = sum_c in_proj_w[p][c] * x_in[b][l][c]
// grid(128, 4), block 256. 16 acc/thread -> 16x fewer LDS reads than 1-acc.
__global__ __launch_bounds__(256) void inproj_kernel(const float* __restrict__ x,
                              const float* __restrict__ w,
                              float* __restrict__ xz) {
    const int b = blockIdx.y;
    const int l0 = blockIdx.x * 32;
    __shared__ float xs[32 * 132];
    for (int idx = threadIdx.x; idx < 32 * 128; idx += 256) {
        int li = idx >> 7, c = idx & 127;
        xs[li * 132 + c] = x[((size_t)(b * 4096 + l0 + li)) * 128 + c];
    }
    __syncthreads();
    const int li = threadIdx.x & 31;
    const int pg = threadIdx.x >> 5;       // 0..7
    const float* xr = xs + li * 132;
    for (int rnd = 0; rnd < 4; ++rnd) {
        const int pbase = rnd * 128 + pg * 16;
        float acc[16];
        #pragma unroll
        for (int j = 0; j < 16; ++j) acc[j] = 0.0f;
        for (int c = 0; c < 128; c += 4) {
            float4 xv = *(const float4*)(xr + c);
            #pragma unroll
            for (int j = 0; j < 16; ++j) {
                float4 wv = *(const float4*)(w + (size_t)(pbase + j) * 128 + c);
                acc[j] += wv.x * xv.x + wv.y * xv.y + wv.z * xv.z + wv.w * xv.w;
            }
        }
        #pragma unroll
        for (int j = 0; j < 16; ++j)
            xz[((size_t)(b * 512 + pbase + j)) * 4096 + l0 + li] = acc[j];
    }
}

// ---------------------------------------------------------------------------
// K2: u_dir[b][d][l] = silu(conv_b[d] + sum_k conv_w[d][k] * xz[b][d][perm(l-3+k)])
__global__ __launch_bounds__(256) void conv_silu_kernel(const float* __restrict__ ws_xz,
                                 float* __restrict__ ws_u,
                                 const float* __restrict__ cw0, const float* __restrict__ cb0,
                                 const float* __restrict__ cw1, const float* __restrict__ cb1,
                                 const float* __restrict__ cw2, const float* __restrict__ cb2) {
    const int d = blockIdx.x, b = blockIdx.y, dir = blockIdx.z;
    const float* cw = (dir == 0) ? cw0 : (dir == 1) ? cw1 : cw2;
    const float* cb = (dir == 0) ? cb0 : (dir == 1) ? cb1 : cb2;
    const float* xrow = ws_xz + ((size_t)(b * 512 + d)) * 4096;
    float* urow = ws_u + (size_t)dir * DIR_SZ + ((size_t)(b * 256 + d)) * 4096;
    const float w0 = cw[d * 4 + 0], w1 = cw[d * 4 + 1], w2 = cw[d * 4 + 2], w3 = cw[d * 4 + 3];
    const float bb = cb[d];
    for (int i = 0; i < 16; ++i) {
        int l = threadIdx.x + i * 256;
        float acc = bb;
        #pragma unroll
        for (int k = 0; k < 4; ++k) {
            int j = l - 3 + k;
            if (j >= 0) {
                float wv = (k == 0) ? w0 : (k == 1) ? w1 : (k == 2) ? w2 : w3;
                acc += wv * xrow[perm_idx(dir, j)];
            }
        }
        urow[l] = siluf_(acc);
    }
}

// ---------------------------------------------------------------------------
// K3: x_dbl = x_proj_w(40x256) @ u-tile; rows 0..7 -> delta; rows 8..39 -> BC[b][l][32].
// ut stored [li][d] (pad 260) so GEMM reads LDS as float4.
__global__ __launch_bounds__(256) void xdbl_kernel(float* __restrict__ ws,
                            const float* __restrict__ xw0, const float* __restrict__ xw1, const float* __restrict__ xw2,
                            const float* __restrict__ dw0, const float* __restrict__ dw1, const float* __restrict__ dw2,
                            const float* __restrict__ db0, const float* __restrict__ db1, const float* __restrict__ db2) {
    const int l0 = blockIdx.x * 32, b = blockIdx.y, dir = blockIdx.z;
    const float* xw = (dir == 0) ? xw0 : (dir == 1) ? xw1 : xw2;
    const float* dw = (dir == 0) ? dw0 : (dir == 1) ? dw1 : dw2;
    const float* db = (dir == 0) ? db0 : (dir == 1) ? db1 : db2;
    const float* u = ws + U_OFF + (size_t)dir * DIR_SZ;
    float* deltab  = ws + DELTA_OFF + (size_t)dir * DIR_SZ;
    float* bc      = ws + BC_OFF + (size_t)dir * BC_SZ;

    __shared__ float ut[32 * 260];   // [li][d], pad 260
    __shared__ float xd[40 * 33];    // [r][li]

    for (int idx = threadIdx.x; idx < 256 * 32; idx += 256) {
        int d = idx >> 5, li = idx & 31;
        ut[li * 260 + d] = u[((size_t)(b * 256 + d)) * 4096 + l0 + li];
    }
    __syncthreads();
    {
        const int rg = threadIdx.x >> 5;   // 0..7 -> rows rg*5..rg*5+4
        const int li = threadIdx.x & 31;
        float acc[5];
        #pragma unroll
        for (int j = 0; j < 5; ++j) acc[j] = 0.0f;
        const float* up = ut + li * 260;
        for (int c = 0; c < 256; c += 4) {
            float4 uv = *(const float4*)(up + c);
            #pragma unroll
            for (int j = 0; j < 5; ++j) {
                float4 wv = *(const float4*)(xw + (size_t)(rg * 5 + j) * 256 + c);
                acc[j] += wv.x * uv.x + wv.y * uv.y + wv.z * uv.z + wv.w * uv.w;
            }
        }
        #pragma unroll
        for (int j = 0; j < 5; ++j) xd[(rg * 5 + j) * 33 + li] = acc[j];
    }
    __syncthreads();
    // B/C rows 8..39 -> (b, l, 32) layout
    for (int idx = threadIdx.x; idx < 32 * 32; idx += 256) {
        int li = idx >> 5, rr = idx & 31;
        bc[((size_t)(b * 4096 + l0 + li)) * 32 + rr] = xd[(8 + rr) * 33 + li];
    }
    // delta = softplus(dt_w @ dt_raw + dt_b)
    for (int o = threadIdx.x; o < 256 * 32; o += 256) {
        int d = o >> 5, li = o & 31;
        float acc = db[d];
        #pragma unroll
        for (int r = 0; r < 8; ++r) acc += dw[d * 8 + r] * xd[r * 33 + li];
        deltab[((size_t)(b * 256 + d)) * 4096 + l0 + li] = softplusf_(acc);
    }
}

// ---------------------------------------------------------------------------
// K4: chunked selective scan. One block per (b,d) row: 256 thr = 16 chunks x 16 states.
// Pass1: local chunk states + decay; LDS prefix -> true initial states; Pass2: rescan + y.
// Writes y DE-PERMUTED (orig l-domain) in place over delta.
__global__ __launch_bounds__(256) void scan_kernel(float* __restrict__ ws,
                            const float* __restrict__ Al0, const float* __restrict__ Dp0,
                            const float* __restrict__ Al1, const float* __restrict__ Dp1,
                            const float* __restrict__ Al2, const float* __restrict__ Dp2) {
    const int d = blockIdx.x, b = blockIdx.y, dir = blockIdx.z;
    const float* Al = (dir == 0) ? Al0 : (dir == 1) ? Al1 : Al2;
    const float* Dp = (dir == 0) ? Dp0 : (dir == 1) ? Dp1 : Dp2;
    const int c = threadIdx.x >> 4;     // chunk 0..15
    const int n = threadIdx.x & 15;     // state 0..15
    const float An = -__expf(Al[d * 16 + n]);
    const float Dd = Dp[d];
    const float* urow = ws + U_OFF + (size_t)dir * DIR_SZ + ((size_t)(b * 256 + d)) * 4096;
    float* drow = ws + DELTA_OFF + (size_t)dir * DIR_SZ + ((size_t)(b * 256 + d)) * 4096;
    const float* bcb = ws + BC_OFF + (size_t)dir * BC_SZ + (size_t)b * 4096 * 32;

    __shared__ float sd[4096];
    __shared__ float su[4096];
    __shared__ float Ssh[16][16];
    __shared__ float Psh[16][16];

    for (int i = threadIdx.x; i < 1024; i += 256) {
        ((float4*)sd)[i] = ((const float4*)drow)[i];
        ((float4*)su)[i] = ((const float4*)urow)[i];
    }
    __syncthreads();

    const int lbase = c * 256;
    // Pass 1: local scan from zero state
    float S = 0.0f, dsum = 0.0f;
    for (int k = 0; k < 256; ++k) {
        int l = lbase + k;
        float dv = sd[l], uv = su[l];
        float Bn = bcb[(size_t)l * 32 + n];
        S = S * __expf(An * dv) + (dv * uv) * Bn;
        dsum += dv;
    }
    Ssh[c][n] = S;
    Psh[c][n] = __expf(An * dsum);
    __syncthreads();
    // Exclusive prefix over chunks
    float h = 0.0f;
    for (int k = 0; k < c; ++k) h = h * Psh[k][n] + Ssh[k][n];

    // Pass 2: rescan with true initial state, produce y
    for (int k2 = 0; k2 < 16; ++k2) {
        float yv = 0.0f;
        #pragma unroll
        for (int kk = 0; kk < 16; ++kk) {
            int l = lbase + k2 * 16 + kk;
            float dv = sd[l], uv = su[l];
            float Bn = bcb[(size_t)l * 32 + n];
            float Cn = bcb[(size_t)l * 32 + 16 + n];
            h = h * __expf(An * dv) + (dv * uv) * Bn;
            float yp = h * Cn;
            yp += __shfl_xor(yp, 1, 16);
            yp += __shfl_xor(yp, 2, 16);
            yp += __shfl_xor(yp, 4, 16);
            yp += __shfl_xor(yp, 8, 16);
            float y = yp + Dd * uv;
            if (kk == n) yv = y;
        }
        int gl = lbase + k2 * 16 + n;          // scan-domain index this lane owns
        drow[perm_idx(dir, gl)] = yv;           // store de-permuted (orig domain)
    }
}

// ---------------------------------------------------------------------------
// K4b: wT[d][o] = out_proj_w[o][d]  (runs after scan; reuses dead BC region)
__global__ __launch_bounds__(256) void transpose_w_kernel(const float* __restrict__ ow,
                                                          float* __restrict__ wT) {
    int idx = blockIdx.x * 256 + threadIdx.x;   // 32768
    int d = idx >> 7, o = idx & 127;
    wT[d * 128 + o] = ow[o * 256 + d];
}

// ---------------------------------------------------------------------------
// K5: y_total[d][l] = silu(z) * (yf+yb+ys) (all already in orig l-domain);
// out[b][l][o] = sum_d wT[d][o] * y_total.  grid(128,4), block 256, 2o x 8li per thread.
__global__ __launch_bounds__(256) void epilogue_kernel(const float* __restrict__ ws,
                                const float* __restrict__ wT,
                                float* __restrict__ out) {
    const int l0 = blockIdx.x * 32, b = blockIdx.y;
    __shared__ float yt[256][36];
    const float* yf = ws + DELTA_OFF;
    const float* yb = ws + DELTA_OFF + DIR_SZ;
    const float* ysd = ws + DELTA_OFF + 2 * DIR_SZ;

    for (int idx = threadIdx.x; idx < 256 * 32; idx += 256) {
        int d = idx >> 5, li = idx & 31;
        int l = l0 + li;
        size_t ro = ((size_t)(b * 256 + d)) * 4096 + l;
        float z  = ws[XZ_OFF + ((size_t)(b * 512 + 256 + d)) * 4096 + l];
        yt[d][li] = (yf[ro] + yb[ro] + ysd[ro]) * siluf_(z);
    }
    __syncthreads();

    const int o0  = (threadIdx.x & 63) * 2;   // 0..126 even
    const int li0 = (threadIdx.x >> 6) * 8;   // 0,8,16,24
    float accA[8], accB[8];
    #pragma unroll
    for (int k = 0; k < 8; ++k) { accA[k] = 0.0f; accB[k] = 0.0f; }
    for (int d = 0; d < 256; ++d) {
        float2 wv = *(const float2*)(wT + d * 128 + o0);
        float4 y0 = *(const float4*)(&yt[d][li0]);
        float4 y1 = *(const float4*)(&yt[d][li0 + 4]);
        accA[0] += wv.x * y0.x; accA[1] += wv.x * y0.y; accA[2] += wv.x * y0.z; accA[3] += wv.x * y0.w;
        accA[4] += wv.x * y1.x; accA[5] += wv.x * y1.y; accA[6] += wv.x * y1.z; accA[7] += wv.x * y1.w;
        accB[0] += wv.y * y0.x; accB[1] += wv.y * y0.y; accB[2] += wv.y * y0.z; accB[3] += wv.y * y0.w;
        accB[4] += wv.y * y1.x; accB[5] += wv.y * y1.y; accB[6] += wv.y * y1.z; accB[7] += wv.y * y1.w;
    }
    #pragma unroll
    for (int k = 0; k < 8; ++k) {
        float2 st; st.x = accA[k]; st.y = accB[k];
        *(float2*)(out + ((size_t)(b * 4096 + l0 + li0 + k)) * 128 + o0) = st;
    }
}

// ---------------------------------------------------------------------------
extern "C" void kernel_launch(void* const* d_in, const int* in_sizes, int n_in,
                              void* d_out, int out_size, void* d_ws, size_t ws_size,
                              hipStream_t stream) {
    const float* x_in = (const float*)d_in[0];
    const float* ipw  = (const float*)d_in[1];
    const float* cw[3]  = {(const float*)d_in[2],  (const float*)d_in[9],  (const float*)d_in[16]};
    const float* cb[3]  = {(const float*)d_in[3],  (const float*)d_in[10], (const float*)d_in[17]};
    const float* xpw[3] = {(const float*)d_in[4],  (const float*)d_in[11], (const float*)d_in[18]};
    const float* dtw[3] = {(const float*)d_in[5],  (const float*)d_in[12], (const float*)d_in[19]};
    const float* dtb[3] = {(const float*)d_in[6],  (const float*)d_in[13], (const float*)d_in[20]};
    const float* alog[3]= {(const float*)d_in[7],  (const float*)d_in[14], (const float*)d_in[21]};
    const float* dp[3]  = {(const float*)d_in[8],  (const float*)d_in[15], (const float*)d_in[22]};
    const float* ow   = (const float*)d_in[23];
    float* ws  = (float*)d_ws;
    float* out = (float*)d_out;

    inproj_kernel<<<dim3(128, 4), 256, 0, stream>>>(x_in, ipw, ws);
    conv_silu_kernel<<<dim3(256, 4, 3), 256, 0, stream>>>(ws, ws + U_OFF,
        cw[0], cb[0], cw[1], cb[1], cw[2], cb[2]);
    xdbl_kernel<<<dim3(128, 4, 3), 256, 0, stream>>>(ws,
        xpw[0], xpw[1], xpw[2], dtw[0], dtw[1], dtw[2], dtb[0], dtb[1], dtb[2]);
    scan_kernel<<<dim3(256, 4, 3), 256, 0, stream>>>(ws,
        alog[0], dp[0], alog[1], dp[1], alog[2], dp[2]);
    transpose_w_kernel<<<dim3(128), 256, 0, stream>>>(ow, ws + WT_OFF);
    epilogue_kernel<<<dim3(128, 4), 256, 0, stream>>>(ws, ws + WT_OFF, out);
}

// Round 3
// 606.111 us; speedup vs baseline: 4.6758x; 1.0056x over previous
//
#include <hip/hip_runtime.h>
#include <math.h>

// Problem constants
// B=4, H=W=64 -> L=4096, DIM=128, D_INNER=256, D_STATE=16, D_CONV=4, DT_RANK=8, NSLICES=16
#define LSEQ 4096

// Workspace layout (floats).
#define XZ_OFF   0ULL
#define XZ_SZ    (4ULL * 512 * 4096)        // xz[b][p][l], l-contiguous
#define U_OFF    (XZ_OFF + XZ_SZ)
#define DIR_SZ   (4ULL * 256 * 4096)        // per direction
#define DELTA_OFF (U_OFF + 3ULL * DIR_SZ)   // delta, overwritten in-place by scan output y (orig l-domain)
#define BC_OFF   (DELTA_OFF + 3ULL * DIR_SZ)
#define BC_SZ    (4ULL * 4096 * 32)         // per dir: B blocked [b][1024][16][4] then C blocked
#define WT_OFF   BC_OFF                     // wT[256][128]; BC dead after scan, reuse region

__device__ __forceinline__ float sigmoidf_(float x) { return 1.0f / (1.0f + __expf(-x)); }
__device__ __forceinline__ float siluf_(float x)    { return x * sigmoidf_(x); }
__device__ __forceinline__ float softplusf_(float x){ return (x > 20.0f) ? x : log1pf(__expf(x)); }

// dir permutation: scan-domain index j -> original-domain index
__device__ __forceinline__ int perm_idx(int dir, int j) {
    if (dir == 0) return j;
    if (dir == 1) return 4095 - j;
    return ((j & 15) << 8) | (j >> 4);   // slice: j = jj*16+s -> s*256+jj
}

// ---------------------------------------------------------------------------
// K1: xz[b][p][l] = sum_c in_proj_w[p][c] * x_in[b][l][c]
__global__ __launch_bounds__(256) void inproj_kernel(const float* __restrict__ x,
                              const float* __restrict__ w,
                              float* __restrict__ xz) {
    const int b = blockIdx.y;
    const int l0 = blockIdx.x * 32;
    __shared__ float xs[32 * 132];
    for (int idx = threadIdx.x; idx < 32 * 128; idx += 256) {
        int li = idx >> 7, c = idx & 127;
        xs[li * 132 + c] = x[((size_t)(b * 4096 + l0 + li)) * 128 + c];
    }
    __syncthreads();
    const int li = threadIdx.x & 31;
    const int pg = threadIdx.x >> 5;       // 0..7
    const float* xr = xs + li * 132;
    for (int rnd = 0; rnd < 4; ++rnd) {
        const int pbase = rnd * 128 + pg * 16;
        float acc[16];
        #pragma unroll
        for (int j = 0; j < 16; ++j) acc[j] = 0.0f;
        for (int c = 0; c < 128; c += 4) {
            float4 xv = *(const float4*)(xr + c);
            #pragma unroll
            for (int j = 0; j < 16; ++j) {
                float4 wv = *(const float4*)(w + (size_t)(pbase + j) * 128 + c);
                acc[j] += wv.x * xv.x + wv.y * xv.y + wv.z * xv.z + wv.w * xv.w;
            }
        }
        #pragma unroll
        for (int j = 0; j < 16; ++j)
            xz[((size_t)(b * 512 + pbase + j)) * 4096 + l0 + li] = acc[j];
    }
}

// ---------------------------------------------------------------------------
// K2 (fused conv+silu+x_proj+dt): per (32-l tile, b, dir).
// Phase A: stage xz window in LDS (fixes dir2 gather amplification).
// Phase B: conv+silu into regs (u), write u to global for scan.
// Phase C: 40x256 GEMM from swizzled LDS u-tile.
// Phase D: delta (softplus(dt)) + B/C in blocked [l4][n][4] layout.
__global__ __launch_bounds__(256) void front_kernel(float* __restrict__ ws,
        const float* __restrict__ xw0, const float* __restrict__ xw1, const float* __restrict__ xw2,
        const float* __restrict__ dw0, const float* __restrict__ dw1, const float* __restrict__ dw2,
        const float* __restrict__ db0, const float* __restrict__ db1, const float* __restrict__ db2,
        const float* __restrict__ cw0, const float* __restrict__ cb0,
        const float* __restrict__ cw1, const float* __restrict__ cb1,
        const float* __restrict__ cw2, const float* __restrict__ cb2) {
    const int l0 = blockIdx.x * 32, b = blockIdx.y, dir = blockIdx.z;
    const float* xw = (dir == 0) ? xw0 : (dir == 1) ? xw1 : xw2;
    const float* dw = (dir == 0) ? dw0 : (dir == 1) ? dw1 : dw2;
    const float* db = (dir == 0) ? db0 : (dir == 1) ? db1 : db2;
    const float* cw = (dir == 0) ? cw0 : (dir == 1) ? cw1 : cw2;
    const float* cb = (dir == 0) ? cb0 : (dir == 1) ? cb1 : cb2;
    const float* xzb = ws + XZ_OFF + (size_t)b * 512 * 4096;
    float* ub      = ws + U_OFF + (size_t)dir * DIR_SZ + (size_t)b * 256 * 4096;
    float* deltab  = ws + DELTA_OFF + (size_t)dir * DIR_SZ + (size_t)b * 256 * 4096;
    float* Bf      = ws + BC_OFF + (size_t)dir * BC_SZ;            // blocked B
    float* Cf      = Bf + BC_SZ / 2;                                // blocked C

    __shared__ float xt[256 * 49];   // staging rows, stride 49 (conflict-free scalar reads)
    __shared__ float xd[40 * 33];
    float* ut = xt;                  // reused after conv: [li][264] swizzled

    // ---- Phase A: stage xz window
    if (dir == 0) {
        for (int idx = threadIdx.x; idx < 256 * 36; idx += 256) {
            int d = idx / 36, k = idx - d * 36;
            int j = l0 - 3 + k;
            xt[d * 49 + k] = (j >= 0 && j < 4096) ? xzb[(size_t)d * 4096 + j] : 0.0f;
        }
    } else if (dir == 1) {
        for (int idx = threadIdx.x; idx < 256 * 36; idx += 256) {
            int d = idx / 36, k = idx - d * 36;
            int j = l0 - 3 + k;
            xt[d * 49 + k] = (j >= 0 && j < 4096) ? xzb[(size_t)d * 4096 + (4095 - j)] : 0.0f;
        }
    } else {
        for (int idx = threadIdx.x; idx < 256 * 48; idx += 256) {
            int d = idx / 48, m = idx - d * 48;
            int s = m & 15, jr = m >> 4;               // jr 0..2
            int jj = (l0 >> 4) - 1 + jr;
            xt[d * 49 + m] = (jj >= 0 && jj < 256) ? xzb[(size_t)d * 4096 + s * 256 + jj] : 0.0f;
        }
    }
    __syncthreads();

    // ---- Phase B: conv + silu, thread = d row
    const int d = threadIdx.x;
    const float w0 = cw[d * 4 + 0], w1 = cw[d * 4 + 1], w2 = cw[d * 4 + 2], w3 = cw[d * 4 + 3];
    const float bb = cb[d];
    float r[32];
    if (dir != 2) {
        float win[35];
        #pragma unroll
        for (int k = 0; k < 35; ++k) win[k] = xt[d * 49 + k];
        #pragma unroll
        for (int li = 0; li < 32; ++li)
            r[li] = siluf_(bb + w0 * win[li] + w1 * win[li + 1] + w2 * win[li + 2] + w3 * win[li + 3]);
    } else {
        float win[48];
        #pragma unroll
        for (int k = 0; k < 48; ++k) win[k] = xt[d * 49 + k];
        #pragma unroll
        for (int li = 0; li < 32; ++li) {
            float acc = bb;
            #pragma unroll
            for (int kk = 0; kk < 4; ++kk) {
                const int e = li + kk - 3;                       // compile-time
                const int slot = (e & 15) + (((e >> 4) + 1) << 4);
                float wv = (kk == 0) ? w0 : (kk == 1) ? w1 : (kk == 2) ? w2 : w3;
                acc += wv * win[slot];
            }
            r[li] = siluf_(acc);
        }
    }
    // write u to global (scan input)
    {
        float* urow = ub + (size_t)d * 4096 + l0;
        #pragma unroll
        for (int q = 0; q < 8; ++q) {
            float4 v; v.x = r[q*4]; v.y = r[q*4+1]; v.z = r[q*4+2]; v.w = r[q*4+3];
            *(float4*)(urow + q * 4) = v;
        }
    }
    __syncthreads();   // all xt reads done
    // store u-tile swizzled: ut[li][ 4*((d>>2)^(li&7)) + (d&3) ]
    #pragma unroll
    for (int li = 0; li < 32; ++li)
        ut[li * 264 + 4 * (((d >> 2) ^ (li & 7))) + (d & 3)] = r[li];
    __syncthreads();

    // ---- Phase C: xd[40][32] = xw(40x256) @ u-tile
    {
        const int rg = threadIdx.x >> 5;   // 0..7 -> rows rg*5..rg*5+4
        const int li = threadIdx.x & 31;
        float acc[5];
        #pragma unroll
        for (int j = 0; j < 5; ++j) acc[j] = 0.0f;
        const float* up = ut + li * 264;
        const int sw = (li & 7);
        for (int c4 = 0; c4 < 64; ++c4) {
            float4 uv = *(const float4*)(up + 4 * (c4 ^ sw));
            const int c = 4 * (c4 ^ sw);
            #pragma unroll
            for (int j = 0; j < 5; ++j) {
                float4 wv = *(const float4*)(xw + (size_t)(rg * 5 + j) * 256 + c);
                acc[j] += wv.x * uv.x + wv.y * uv.y + wv.z * uv.z + wv.w * uv.w;
            }
        }
        #pragma unroll
        for (int j = 0; j < 5; ++j) xd[(rg * 5 + j) * 33 + li] = acc[j];
    }
    __syncthreads();

    // ---- Phase D: B/C blocked writes (wave-coalesced) + delta
    {
        const int wv = threadIdx.x >> 6;       // wave 0..3
        const int lane = threadIdx.x & 63;
        const int n = lane >> 2, lq = lane & 3;
        #pragma unroll
        for (int j = 0; j < 2; ++j) {
            int l4 = (l0 >> 2) + j * 4 + wv;
            int li = (j * 4 + wv) * 4 + lq;
            size_t base = (((size_t)b * 1024 + l4) * 16 + n) * 4 + lq;
            Bf[base] = xd[(8 + n) * 33 + li];
            Cf[base] = xd[(24 + n) * 33 + li];
        }
    }
    for (int o = threadIdx.x; o < 256 * 32; o += 256) {
        int dd = o >> 5, li = o & 31;
        float acc = db[dd];
        #pragma unroll
        for (int rr = 0; rr < 8; ++rr) acc += dw[dd * 8 + rr] * xd[rr * 33 + li];
        deltab[(size_t)dd * 4096 + l0 + li] = softplusf_(acc);
    }
}

// ---------------------------------------------------------------------------
// K3: chunked selective scan. Block = (b,d,dir) row: 512 thr = 32 chunks x 16 states.
// LDS: (delta, delta*u) float2, chunk stride 264 floats (conflict-free).
// B/C read as float4 from blocked layout. Writes y de-permuted over delta.
__global__ __launch_bounds__(512) void scan_kernel(float* __restrict__ ws,
                            const float* __restrict__ Al0, const float* __restrict__ Dp0,
                            const float* __restrict__ Al1, const float* __restrict__ Dp1,
                            const float* __restrict__ Al2, const float* __restrict__ Dp2) {
    const int d = blockIdx.x, b = blockIdx.y, dir = blockIdx.z;
    const float* Al = (dir == 0) ? Al0 : (dir == 1) ? Al1 : Al2;
    const float* Dp = (dir == 0) ? Dp0 : (dir == 1) ? Dp1 : Dp2;
    const int c = threadIdx.x >> 4;     // chunk 0..31
    const int n = threadIdx.x & 15;     // state 0..15
    const float An = -__expf(Al[d * 16 + n]);
    const float Dd = Dp[d];
    const float* urow = ws + U_OFF + (size_t)dir * DIR_SZ + ((size_t)(b * 256 + d)) * 4096;
    float* drow = ws + DELTA_OFF + (size_t)dir * DIR_SZ + ((size_t)(b * 256 + d)) * 4096;

    __shared__ float sdu[32 * 264];     // [chunk][(dv,du) x128 + pad]
    __shared__ float Ssh[32 * 16];
    __shared__ float Psh[32 * 16];

    {
        const float4* d4 = (const float4*)drow;
        const float4* u4 = (const float4*)urow;
        for (int i = threadIdx.x; i < 1024; i += 512) {
            float4 dv = d4[i], uv = u4[i];
            int l = i * 4;
            float* p = sdu + (l >> 7) * 264 + (l & 127) * 2;
            float4 a, bq;
            a.x = dv.x; a.y = dv.x * uv.x; a.z = dv.y; a.w = dv.y * uv.y;
            bq.x = dv.z; bq.y = dv.z * uv.z; bq.z = dv.w; bq.w = dv.w * uv.w;
            *(float4*)(p) = a; *(float4*)(p + 4) = bq;
        }
    }
    __syncthreads();

    const float4* Bq = (const float4*)(ws + BC_OFF + (size_t)dir * BC_SZ)
                       + ((size_t)b * 1024 + c * 32) * 16 + n;
    const float4* Cq = (const float4*)(ws + BC_OFF + (size_t)dir * BC_SZ + BC_SZ / 2)
                       + ((size_t)b * 1024 + c * 32) * 16 + n;
    const float4* sp = (const float4*)(sdu + c * 264);

    // Pass 1: local scan + decay-sum
    float S = 0.0f, dsum = 0.0f;
    #pragma unroll 8
    for (int k4 = 0; k4 < 32; ++k4) {
        float4 a = sp[k4 * 2], bq = sp[k4 * 2 + 1];
        float4 Bv = Bq[(size_t)k4 * 16];
        dsum += a.x + a.z + bq.x + bq.z;
        S = S * __expf(An * a.x) + a.y * Bv.x;
        S = S * __expf(An * a.z) + a.w * Bv.y;
        S = S * __expf(An * bq.x) + bq.y * Bv.z;
        S = S * __expf(An * bq.z) + bq.w * Bv.w;
    }
    Ssh[c * 16 + n] = S;
    Psh[c * 16 + n] = __expf(An * dsum);
    __syncthreads();
    float h = 0.0f;
    for (int k = 0; k < c; ++k) h = h * Psh[k * 16 + n] + Ssh[k * 16 + n];

    // Pass 2: rescan, produce y (groups of 16 steps; lane owns local==n)
    for (int g = 0; g < 8; ++g) {
        float uown = urow[c * 128 + g * 16 + n];
        float yv = 0.0f;
        #pragma unroll
        for (int k4 = 0; k4 < 4; ++k4) {
            float4 a = sp[g * 8 + k4 * 2], bq = sp[g * 8 + k4 * 2 + 1];
            float4 Bv = Bq[(size_t)(g * 4 + k4) * 16];
            float4 Cv = Cq[(size_t)(g * 4 + k4) * 16];
            #pragma unroll
            for (int j = 0; j < 4; ++j) {
                float dv = (j == 0) ? a.x : (j == 1) ? a.z : (j == 2) ? bq.x : bq.z;
                float du = (j == 0) ? a.y : (j == 1) ? a.w : (j == 2) ? bq.y : bq.w;
                float Bn = (j == 0) ? Bv.x : (j == 1) ? Bv.y : (j == 2) ? Bv.z : Bv.w;
                float Cn = (j == 0) ? Cv.x : (j == 1) ? Cv.y : (j == 2) ? Cv.z : Cv.w;
                h = h * __expf(An * dv) + du * Bn;
                float yp = h * Cn;
                yp += __shfl_xor(yp, 1, 16);
                yp += __shfl_xor(yp, 2, 16);
                yp += __shfl_xor(yp, 4, 16);
                yp += __shfl_xor(yp, 8, 16);
                if (k4 * 4 + j == n) yv = yp;
            }
        }
        int gl = c * 128 + g * 16 + n;
        drow[perm_idx(dir, gl)] = yv + Dd * uown;
    }
}

// ---------------------------------------------------------------------------
// K3b: wT[d][o] = out_proj_w[o][d]  (after scan; reuses dead BC region)
__global__ __launch_bounds__(256) void transpose_w_kernel(const float* __restrict__ ow,
                                                          float* __restrict__ wT) {
    int idx = blockIdx.x * 256 + threadIdx.x;   // 32768
    int d = idx >> 7, o = idx & 127;
    wT[d * 128 + o] = ow[o * 256 + d];
}

// ---------------------------------------------------------------------------
// K4: y_total = silu(z)*(yf+yb+ys); out = wT^T @ y_total.
__global__ __launch_bounds__(256) void epilogue_kernel(const float* __restrict__ ws,
                                const float* __restrict__ wT,
                                float* __restrict__ out) {
    const int l0 = blockIdx.x * 32, b = blockIdx.y;
    __shared__ float yt[256][36];
    const float* yf = ws + DELTA_OFF;
    const float* yb = ws + DELTA_OFF + DIR_SZ;
    const float* ysd = ws + DELTA_OFF + 2 * DIR_SZ;

    for (int idx = threadIdx.x; idx < 256 * 32; idx += 256) {
        int d = idx >> 5, li = idx & 31;
        int l = l0 + li;
        size_t ro = ((size_t)(b * 256 + d)) * 4096 + l;
        float z  = ws[XZ_OFF + ((size_t)(b * 512 + 256 + d)) * 4096 + l];
        yt[d][li] = (yf[ro] + yb[ro] + ysd[ro]) * siluf_(z);
    }
    __syncthreads();

    const int o0  = (threadIdx.x & 63) * 2;   // 0..126 even
    const int li0 = (threadIdx.x >> 6) * 8;   // 0,8,16,24
    float accA[8], accB[8];
    #pragma unroll
    for (int k = 0; k < 8; ++k) { accA[k] = 0.0f; accB[k] = 0.0f; }
    for (int d = 0; d < 256; ++d) {
        float2 wv = *(const float2*)(wT + d * 128 + o0);
        float4 y0 = *(const float4*)(&yt[d][li0]);
        float4 y1 = *(const float4*)(&yt[d][li0 + 4]);
        accA[0] += wv.x * y0.x; accA[1] += wv.x * y0.y; accA[2] += wv.x * y0.z; accA[3] += wv.x * y0.w;
        accA[4] += wv.x * y1.x; accA[5] += wv.x * y1.y; accA[6] += wv.x * y1.z; accA[7] += wv.x * y1.w;
        accB[0] += wv.y * y0.x; accB[1] += wv.y * y0.y; accB[2] += wv.y * y0.z; accB[3] += wv.y * y0.w;
        accB[4] += wv.y * y1.x; accB[5] += wv.y * y1.y; accB[6] += wv.y * y1.z; accB[7] += wv.y * y1.w;
    }
    #pragma unroll
    for (int k = 0; k < 8; ++k) {
        float2 st; st.x = accA[k]; st.y = accB[k];
        *(float2*)(out + ((size_t)(b * 4096 + l0 + li0 + k)) * 128 + o0) = st;
    }
}

// ---------------------------------------------------------------------------
extern "C" void kernel_launch(void* const* d_in, const int* in_sizes, int n_in,
                              void* d_out, int out_size, void* d_ws, size_t ws_size,
                              hipStream_t stream) {
    const float* x_in = (const float*)d_in[0];
    const float* ipw  = (const float*)d_in[1];
    const float* cw[3]  = {(const float*)d_in[2],  (const float*)d_in[9],  (const float*)d_in[16]};
    const float* cb[3]  = {(const float*)d_in[3],  (const float*)d_in[10], (const float*)d_in[17]};
    const float* xpw[3] = {(const float*)d_in[4],  (const float*)d_in[11], (const float*)d_in[18]};
    const float* dtw[3] = {(const float*)d_in[5],  (const float*)d_in[12], (const float*)d_in[19]};
    const float* dtb[3] = {(const float*)d_in[6],  (const float*)d_in[13], (const float*)d_in[20]};
    const float* alog[3]= {(const float*)d_in[7],  (const float*)d_in[14], (const float*)d_in[21]};
    const float* dp[3]  = {(const float*)d_in[8],  (const float*)d_in[15], (const float*)d_in[22]};
    const float* ow   = (const float*)d_in[23];
    float* ws  = (float*)d_ws;
    float* out = (float*)d_out;

    inproj_kernel<<<dim3(128, 4), 256, 0, stream>>>(x_in, ipw, ws);
    front_kernel<<<dim3(128, 4, 3), 256, 0, stream>>>(ws,
        xpw[0], xpw[1], xpw[2], dtw[0], dtw[1], dtw[2], dtb[0], dtb[1], dtb[2],
        cw[0], cb[0], cw[1], cb[1], cw[2], cb[2]);
    scan_kernel<<<dim3(256, 4, 3), 512, 0, stream>>>(ws,
        alog[0], dp[0], alog[1], dp[1], alog[2], dp[2]);
    transpose_w_kernel<<<dim3(128), 256, 0, stream>>>(ow, ws + WT_OFF);
    epilogue_kernel<<<dim3(128, 4), 256, 0, stream>>>(ws, ws + WT_OFF, out);
}

// Round 4
// 533.776 us; speedup vs baseline: 5.3094x; 1.1355x over previous
//
#include <hip/hip_runtime.h>
#include <math.h>

// Problem constants
// B=4, H=W=64 -> L=4096, DIM=128, D_INNER=256, D_STATE=16, D_CONV=4, DT_RANK=8, NSLICES=16
#define LSEQ 4096

// Workspace layout (floats). Total = 35,127,296 floats (~134 MB, proven to fit)
#define XZ_OFF   0ULL
#define XZ_SZ    (4ULL * 512 * 4096)        // xz[b][p][l], l-contiguous
#define U_OFF    (XZ_OFF + XZ_SZ)
#define DIR_SZ   (4ULL * 256 * 4096)        // per direction
#define DELTA_OFF (U_OFF + 3ULL * DIR_SZ)   // delta, overwritten in-place by scan output y (orig l-domain)
#define BC_OFF   (DELTA_OFF + 3ULL * DIR_SZ)
#define BC_SZ    (4ULL * 4096 * 32)         // per dir: B blocked [b][1024][16][4] then C blocked
#define WT_OFF   BC_OFF                     // wT[256][128]; BC dead after scan, reuse region

__device__ __forceinline__ float sigmoidf_(float x) { return 1.0f / (1.0f + __expf(-x)); }
__device__ __forceinline__ float siluf_(float x)    { return x * sigmoidf_(x); }
__device__ __forceinline__ float softplusf_(float x){ return (x > 20.0f) ? x : log1pf(__expf(x)); }

// dir permutation: scan-domain index j -> original-domain index
__device__ __forceinline__ int perm_idx(int dir, int j) {
    if (dir == 0) return j;
    if (dir == 1) return 4095 - j;
    return ((j & 15) << 8) | (j >> 4);   // slice: j = jj*16+s -> s*256+jj
}

// DPP cross-lane move (VALU pipe, no LDS). ctrl must be a literal.
#define DPP_MOV(x, ctrl) __int_as_float(__builtin_amdgcn_update_dpp(0, __float_as_int(x), (ctrl), 0xF, 0xF, true))
// 16-lane butterfly sum via DPP: quad xor1, quad xor2, half-mirror, mirror.
__device__ __forceinline__ float dpp_sum16(float x) {
    x += DPP_MOV(x, 0xB1);    // quad_perm [1,0,3,2]
    x += DPP_MOV(x, 0x4E);    // quad_perm [2,3,0,1]
    x += DPP_MOV(x, 0x141);   // row_half_mirror
    x += DPP_MOV(x, 0x140);   // row_mirror (within 16-lane row)
    return x;
}

// ---------------------------------------------------------------------------
// K1: xz[b][p][l] = sum_c in_proj_w[p][c] * x_in[b][l][c]
__global__ __launch_bounds__(256) void inproj_kernel(const float* __restrict__ x,
                              const float* __restrict__ w,
                              float* __restrict__ xz) {
    const int b = blockIdx.y;
    const int l0 = blockIdx.x * 32;
    __shared__ float xs[32 * 132];
    for (int idx = threadIdx.x; idx < 32 * 128; idx += 256) {
        int li = idx >> 7, c = idx & 127;
        xs[li * 132 + c] = x[((size_t)(b * 4096 + l0 + li)) * 128 + c];
    }
    __syncthreads();
    const int li = threadIdx.x & 31;
    const int pg = threadIdx.x >> 5;       // 0..7
    const float* xr = xs + li * 132;
    for (int rnd = 0; rnd < 4; ++rnd) {
        const int pbase = rnd * 128 + pg * 16;
        float acc[16];
        #pragma unroll
        for (int j = 0; j < 16; ++j) acc[j] = 0.0f;
        for (int c = 0; c < 128; c += 4) {
            float4 xv = *(const float4*)(xr + c);
            #pragma unroll
            for (int j = 0; j < 16; ++j) {
                float4 wv = *(const float4*)(w + (size_t)(pbase + j) * 128 + c);
                acc[j] += wv.x * xv.x + wv.y * xv.y + wv.z * xv.z + wv.w * xv.w;
            }
        }
        #pragma unroll
        for (int j = 0; j < 16; ++j)
            xz[((size_t)(b * 512 + pbase + j)) * 4096 + l0 + li] = acc[j];
    }
}

// ---------------------------------------------------------------------------
// K2a: dir2 conv+silu via in-LDS row transpose. Block = one (b,d) row.
// Reads xz row coalesced, permuted reads from padded LDS, coalesced u writes.
__global__ __launch_bounds__(256) void conv2_kernel(const float* __restrict__ ws_xz,
                                 float* __restrict__ ws_u2,
                                 const float* __restrict__ cw2, const float* __restrict__ cb2) {
    const int d = blockIdx.x, b = blockIdx.y;
    const float* xrow = ws_xz + ((size_t)(b * 512 + d)) * 4096;
    float* urow = ws_u2 + ((size_t)(b * 256 + d)) * 4096;
    __shared__ float sh[16 * 260];   // sh[s][jj], pad 260
    for (int i = threadIdx.x; i < 4096; i += 256)
        sh[(i >> 8) * 260 + (i & 255)] = xrow[i];
    __syncthreads();
    const float w0 = cw2[d * 4 + 0], w1 = cw2[d * 4 + 1], w2 = cw2[d * 4 + 2], w3 = cw2[d * 4 + 3];
    const float bb = cb2[d];
    const int t = threadIdx.x;       // j = 16t .. 16t+15
    float xwin[19];                  // x~[16t-3 .. 16t+15]
    #pragma unroll
    for (int k = 0; k < 19; ++k) {
        int j = 16 * t - 3 + k;
        xwin[k] = (j >= 0) ? sh[(j & 15) * 260 + (j >> 4)] : 0.0f;
    }
    float r[16];
    #pragma unroll
    for (int i = 0; i < 16; ++i)
        r[i] = siluf_(bb + w0 * xwin[i] + w1 * xwin[i + 1] + w2 * xwin[i + 2] + w3 * xwin[i + 3]);
    #pragma unroll
    for (int q = 0; q < 4; ++q) {
        float4 v; v.x = r[q*4]; v.y = r[q*4+1]; v.z = r[q*4+2]; v.w = r[q*4+3];
        *(float4*)(urow + 16 * t + q * 4) = v;
    }
}

// ---------------------------------------------------------------------------
// K2b (fused conv+silu+x_proj+dt): per (32-l tile, b, dir).
// dir0/1: stage xz window COALESCED (140B segments), conv in regs, write u.
// dir2: load precomputed u tile (coalesced). Then 40x256 GEMM + delta + B/C.
__global__ __launch_bounds__(256) void front_kernel(float* __restrict__ ws,
        const float* __restrict__ xw0, const float* __restrict__ xw1, const float* __restrict__ xw2,
        const float* __restrict__ dw0, const float* __restrict__ dw1, const float* __restrict__ dw2,
        const float* __restrict__ db0, const float* __restrict__ db1, const float* __restrict__ db2,
        const float* __restrict__ cw0, const float* __restrict__ cb0,
        const float* __restrict__ cw1, const float* __restrict__ cb1) {
    const int l0 = blockIdx.x * 32, b = blockIdx.y, dir = blockIdx.z;
    const float* xw = (dir == 0) ? xw0 : (dir == 1) ? xw1 : xw2;
    const float* dw = (dir == 0) ? dw0 : (dir == 1) ? dw1 : dw2;
    const float* db = (dir == 0) ? db0 : (dir == 1) ? db1 : db2;
    const float* xzb = ws + XZ_OFF + (size_t)b * 512 * 4096;
    float* ub      = ws + U_OFF + (size_t)dir * DIR_SZ + (size_t)b * 256 * 4096;
    float* deltab  = ws + DELTA_OFF + (size_t)dir * DIR_SZ + (size_t)b * 256 * 4096;
    float* Bf      = ws + BC_OFF + (size_t)dir * BC_SZ;            // blocked B
    float* Cf      = Bf + BC_SZ / 2;                                // blocked C

    __shared__ float xt[256 * 41];   // staging rows [d][k], stride 41 (conflict-free reads)
    __shared__ float xd[40 * 33];
    float* ut = xt;                  // reused after conv: [li][264] swizzled

    const int d = threadIdx.x;
    float r[32];

    if (dir != 2) {
        const float* cw = (dir == 0) ? cw0 : cw1;
        const float* cb = (dir == 0) ? cb0 : cb1;
        // ---- stage window [d][k], k=0..34 -> j = l0-3+k  (coalesced 140B segments)
        for (int idx = threadIdx.x; idx < 256 * 35; idx += 256) {
            int dd = idx / 35, k = idx - dd * 35;
            int j = l0 - 3 + k;
            float v = 0.0f;
            if (j >= 0) v = xzb[(size_t)dd * 4096 + ((dir == 1) ? (4095 - j) : j)];
            xt[dd * 41 + k] = v;
        }
        __syncthreads();
        // ---- conv + silu, thread = d row
        const float w0 = cw[d * 4 + 0], w1 = cw[d * 4 + 1], w2 = cw[d * 4 + 2], w3 = cw[d * 4 + 3];
        const float bb = cb[d];
        float win[35];
        #pragma unroll
        for (int k = 0; k < 35; ++k) win[k] = xt[d * 41 + k];
        #pragma unroll
        for (int li = 0; li < 32; ++li)
            r[li] = siluf_(bb + w0 * win[li] + w1 * win[li + 1] + w2 * win[li + 2] + w3 * win[li + 3]);
        // write u (scan input)
        float* urow = ub + (size_t)d * 4096 + l0;
        #pragma unroll
        for (int q = 0; q < 8; ++q) {
            float4 v; v.x = r[q*4]; v.y = r[q*4+1]; v.z = r[q*4+2]; v.w = r[q*4+3];
            *(float4*)(urow + q * 4) = v;
        }
        __syncthreads();   // all xt reads done before ut overwrite
    } else {
        // dir2: u already computed by conv2_kernel; load tile (coalesced per-thread float4)
        const float* urow = ub + (size_t)d * 4096 + l0;
        #pragma unroll
        for (int q = 0; q < 8; ++q) {
            float4 v = *(const float4*)(urow + q * 4);
            r[q*4] = v.x; r[q*4+1] = v.y; r[q*4+2] = v.z; r[q*4+3] = v.w;
        }
        __syncthreads();
    }

    // store u-tile swizzled: ut[li][ 4*((d>>2)^(li&7)) + (d&3) ]
    #pragma unroll
    for (int li = 0; li < 32; ++li)
        ut[li * 264 + 4 * (((d >> 2) ^ (li & 7))) + (d & 3)] = r[li];
    __syncthreads();

    // ---- 40x256 GEMM: xd[40][32] = xw @ u-tile
    {
        const int rg = threadIdx.x >> 5;   // 0..7 -> rows rg*5..rg*5+4
        const int li = threadIdx.x & 31;
        float acc[5];
        #pragma unroll
        for (int j = 0; j < 5; ++j) acc[j] = 0.0f;
        const float* up = ut + li * 264;
        const int sw = (li & 7);
        for (int c4 = 0; c4 < 64; ++c4) {
            float4 uv = *(const float4*)(up + 4 * (c4 ^ sw));
            const int c = 4 * (c4 ^ sw);
            #pragma unroll
            for (int j = 0; j < 5; ++j) {
                float4 wv = *(const float4*)(xw + (size_t)(rg * 5 + j) * 256 + c);
                acc[j] += wv.x * uv.x + wv.y * uv.y + wv.z * uv.z + wv.w * uv.w;
            }
        }
        #pragma unroll
        for (int j = 0; j < 5; ++j) xd[(rg * 5 + j) * 33 + li] = acc[j];
    }
    __syncthreads();

    // ---- B/C blocked writes (wave-coalesced) + delta
    {
        const int wv = threadIdx.x >> 6;       // wave 0..3
        const int lane = threadIdx.x & 63;
        const int n = lane >> 2, lq = lane & 3;
        #pragma unroll
        for (int j = 0; j < 2; ++j) {
            int l4 = (l0 >> 2) + j * 4 + wv;
            int li = (j * 4 + wv) * 4 + lq;
            size_t base = (((size_t)b * 1024 + l4) * 16 + n) * 4 + lq;
            Bf[base] = xd[(8 + n) * 33 + li];
            Cf[base] = xd[(24 + n) * 33 + li];
        }
    }
    for (int o = threadIdx.x; o < 256 * 32; o += 256) {
        int dd = o >> 5, li = o & 31;
        float acc = db[dd];
        #pragma unroll
        for (int rr = 0; rr < 8; ++rr) acc += dw[dd * 8 + rr] * xd[rr * 33 + li];
        deltab[(size_t)dd * 4096 + l0 + li] = softplusf_(acc);
    }
}

// ---------------------------------------------------------------------------
// K3: chunked selective scan. Block = (b,d,dir) row: 512 thr = 32 chunks x 16 states.
// LDS: (delta, delta*u) float2, chunk stride 264 (conflict-free). B/C float4 blocked.
// y-reduction via DPP (VALU pipe) instead of ds_swizzle. Writes y de-permuted.
__global__ __launch_bounds__(512) void scan_kernel(float* __restrict__ ws,
                            const float* __restrict__ Al0, const float* __restrict__ Dp0,
                            const float* __restrict__ Al1, const float* __restrict__ Dp1,
                            const float* __restrict__ Al2, const float* __restrict__ Dp2) {
    const int d = blockIdx.x, b = blockIdx.y, dir = blockIdx.z;
    const float* Al = (dir == 0) ? Al0 : (dir == 1) ? Al1 : Al2;
    const float* Dp = (dir == 0) ? Dp0 : (dir == 1) ? Dp1 : Dp2;
    const int c = threadIdx.x >> 4;     // chunk 0..31
    const int n = threadIdx.x & 15;     // state 0..15
    const float An = -__expf(Al[d * 16 + n]);
    const float Dd = Dp[d];
    const float* urow = ws + U_OFF + (size_t)dir * DIR_SZ + ((size_t)(b * 256 + d)) * 4096;
    float* drow = ws + DELTA_OFF + (size_t)dir * DIR_SZ + ((size_t)(b * 256 + d)) * 4096;

    __shared__ float sdu[32 * 264];     // [chunk][(dv,du) x128 + pad]
    __shared__ float Ssh[32 * 16];
    __shared__ float Psh[32 * 16];

    {
        const float4* d4 = (const float4*)drow;
        const float4* u4 = (const float4*)urow;
        for (int i = threadIdx.x; i < 1024; i += 512) {
            float4 dv = d4[i], uv = u4[i];
            int l = i * 4;
            float* p = sdu + (l >> 7) * 264 + (l & 127) * 2;
            float4 a, bq;
            a.x = dv.x; a.y = dv.x * uv.x; a.z = dv.y; a.w = dv.y * uv.y;
            bq.x = dv.z; bq.y = dv.z * uv.z; bq.z = dv.w; bq.w = dv.w * uv.w;
            *(float4*)(p) = a; *(float4*)(p + 4) = bq;
        }
    }
    __syncthreads();

    const float4* Bq = (const float4*)(ws + BC_OFF + (size_t)dir * BC_SZ)
                       + ((size_t)b * 1024 + c * 32) * 16 + n;
    const float4* Cq = (const float4*)(ws + BC_OFF + (size_t)dir * BC_SZ + BC_SZ / 2)
                       + ((size_t)b * 1024 + c * 32) * 16 + n;
    const float4* sp = (const float4*)(sdu + c * 264);

    // Pass 1: local scan + decay-sum
    float S = 0.0f, dsum = 0.0f;
    #pragma unroll 8
    for (int k4 = 0; k4 < 32; ++k4) {
        float4 a = sp[k4 * 2], bq = sp[k4 * 2 + 1];
        float4 Bv = Bq[(size_t)k4 * 16];
        dsum += a.x + a.z + bq.x + bq.z;
        S = S * __expf(An * a.x) + a.y * Bv.x;
        S = S * __expf(An * a.z) + a.w * Bv.y;
        S = S * __expf(An * bq.x) + bq.y * Bv.z;
        S = S * __expf(An * bq.z) + bq.w * Bv.w;
    }
    Ssh[c * 16 + n] = S;
    Psh[c * 16 + n] = __expf(An * dsum);
    __syncthreads();
    float h = 0.0f;
    for (int k = 0; k < c; ++k) h = h * Psh[k * 16 + n] + Ssh[k * 16 + n];

    // Pass 2: rescan, produce y (groups of 16 steps; lane keeps local step == n)
    for (int g = 0; g < 8; ++g) {
        float uown = urow[c * 128 + g * 16 + n];
        float yv = 0.0f;
        #pragma unroll
        for (int k4 = 0; k4 < 4; ++k4) {
            float4 a = sp[g * 8 + k4 * 2], bq = sp[g * 8 + k4 * 2 + 1];
            float4 Bv = Bq[(size_t)(g * 4 + k4) * 16];
            float4 Cv = Cq[(size_t)(g * 4 + k4) * 16];
            #pragma unroll
            for (int j = 0; j < 4; ++j) {
                float dv = (j == 0) ? a.x : (j == 1) ? a.z : (j == 2) ? bq.x : bq.z;
                float du = (j == 0) ? a.y : (j == 1) ? a.w : (j == 2) ? bq.y : bq.w;
                float Bn = (j == 0) ? Bv.x : (j == 1) ? Bv.y : (j == 2) ? Bv.z : Bv.w;
                float Cn = (j == 0) ? Cv.x : (j == 1) ? Cv.y : (j == 2) ? Cv.z : Cv.w;
                h = h * __expf(An * dv) + du * Bn;
                float yp = dpp_sum16(h * Cn);          // VALU-pipe butterfly
                if (k4 * 4 + j == n) yv = yp;
            }
        }
        int gl = c * 128 + g * 16 + n;
        drow[perm_idx(dir, gl)] = yv + Dd * uown;
    }
}

// ---------------------------------------------------------------------------
// K3b: wT[d][o] = out_proj_w[o][d]  (after scan; reuses dead BC region)
__global__ __launch_bounds__(256) void transpose_w_kernel(const float* __restrict__ ow,
                                                          float* __restrict__ wT) {
    int idx = blockIdx.x * 256 + threadIdx.x;   // 32768
    int d = idx >> 7, o = idx & 127;
    wT[d * 128 + o] = ow[o * 256 + d];
}

// ---------------------------------------------------------------------------
// K4: y_total = silu(z)*(yf+yb+ys); out = wT^T @ y_total.
__global__ __launch_bounds__(256) void epilogue_kernel(const float* __restrict__ ws,
                                const float* __restrict__ wT,
                                float* __restrict__ out) {
    const int l0 = blockIdx.x * 32, b = blockIdx.y;
    __shared__ float yt[256][36];
    const float* yf = ws + DELTA_OFF;
    const float* yb = ws + DELTA_OFF + DIR_SZ;
    const float* ysd = ws + DELTA_OFF + 2 * DIR_SZ;

    for (int idx = threadIdx.x; idx < 256 * 32; idx += 256) {
        int d = idx >> 5, li = idx & 31;
        int l = l0 + li;
        size_t ro = ((size_t)(b * 256 + d)) * 4096 + l;
        float z  = ws[XZ_OFF + ((size_t)(b * 512 + 256 + d)) * 4096 + l];
        yt[d][li] = (yf[ro] + yb[ro] + ysd[ro]) * siluf_(z);
    }
    __syncthreads();

    const int o0  = (threadIdx.x & 63) * 2;   // 0..126 even
    const int li0 = (threadIdx.x >> 6) * 8;   // 0,8,16,24
    float accA[8], accB[8];
    #pragma unroll
    for (int k = 0; k < 8; ++k) { accA[k] = 0.0f; accB[k] = 0.0f; }
    for (int d = 0; d < 256; ++d) {
        float2 wv = *(const float2*)(wT + d * 128 + o0);
        float4 y0 = *(const float4*)(&yt[d][li0]);
        float4 y1 = *(const float4*)(&yt[d][li0 + 4]);
        accA[0] += wv.x * y0.x; accA[1] += wv.x * y0.y; accA[2] += wv.x * y0.z; accA[3] += wv.x * y0.w;
        accA[4] += wv.x * y1.x; accA[5] += wv.x * y1.y; accA[6] += wv.x * y1.z; accA[7] += wv.x * y1.w;
        accB[0] += wv.y * y0.x; accB[1] += wv.y * y0.y; accB[2] += wv.y * y0.z; accB[3] += wv.y * y0.w;
        accB[4] += wv.y * y1.x; accB[5] += wv.y * y1.y; accB[6] += wv.y * y1.z; accB[7] += wv.y * y1.w;
    }
    #pragma unroll
    for (int k = 0; k < 8; ++k) {
        float2 st; st.x = accA[k]; st.y = accB[k];
        *(float2*)(out + ((size_t)(b * 4096 + l0 + li0 + k)) * 128 + o0) = st;
    }
}

// ---------------------------------------------------------------------------
extern "C" void kernel_launch(void* const* d_in, const int* in_sizes, int n_in,
                              void* d_out, int out_size, void* d_ws, size_t ws_size,
                              hipStream_t stream) {
    const float* x_in = (const float*)d_in[0];
    const float* ipw  = (const float*)d_in[1];
    const float* cw[3]  = {(const float*)d_in[2],  (const float*)d_in[9],  (const float*)d_in[16]};
    const float* cb[3]  = {(const float*)d_in[3],  (const float*)d_in[10], (const float*)d_in[17]};
    const float* xpw[3] = {(const float*)d_in[4],  (const float*)d_in[11], (const float*)d_in[18]};
    const float* dtw[3] = {(const float*)d_in[5],  (const float*)d_in[12], (const float*)d_in[19]};
    const float* dtb[3] = {(const float*)d_in[6],  (const float*)d_in[13], (const float*)d_in[20]};
    const float* alog[3]= {(const float*)d_in[7],  (const float*)d_in[14], (const float*)d_in[21]};
    const float* dp[3]  = {(const float*)d_in[8],  (const float*)d_in[15], (const float*)d_in[22]};
    const float* ow   = (const float*)d_in[23];
    float* ws  = (float*)d_ws;
    float* out = (float*)d_out;

    inproj_kernel<<<dim3(128, 4), 256, 0, stream>>>(x_in, ipw, ws);
    conv2_kernel<<<dim3(256, 4), 256, 0, stream>>>(ws, ws + U_OFF + 2 * DIR_SZ, cw[2], cb[2]);
    front_kernel<<<dim3(128, 4, 3), 256, 0, stream>>>(ws,
        xpw[0], xpw[1], xpw[2], dtw[0], dtw[1], dtw[2], dtb[0], dtb[1], dtb[2],
        cw[0], cb[0], cw[1], cb[1]);
    scan_kernel<<<dim3(256, 4, 3), 512, 0, stream>>>(ws,
        alog[0], dp[0], alog[1], dp[1], alog[2], dp[2]);
    transpose_w_kernel<<<dim3(128), 256, 0, stream>>>(ow, ws + WT_OFF);
    epilogue_kernel<<<dim3(128, 4), 256, 0, stream>>>(ws, ws + WT_OFF, out);
}

// Round 5
// 446.697 us; speedup vs baseline: 6.3444x; 1.1949x over previous
//
#include <hip/hip_runtime.h>
#include <math.h>

// Problem constants
// B=4, H=W=64 -> L=4096, DIM=128, D_INNER=256, D_STATE=16, D_CONV=4, DT_RANK=8, NSLICES=16
#define LSEQ 4096

// Workspace layout (floats). Total ~134 MB (proven to fit)
#define XZ_OFF   0ULL
#define XZ_SZ    (4ULL * 512 * 4096)        // xz[b][p][l], l-contiguous
#define U_OFF    (XZ_OFF + XZ_SZ)
#define DIR_SZ   (4ULL * 256 * 4096)        // per direction
#define DELTA_OFF (U_OFF + 3ULL * DIR_SZ)   // delta; also holds wT_in before front runs
#define BC_OFF   (DELTA_OFF + 3ULL * DIR_SZ)
#define BC_SZ    (4ULL * 4096 * 32)         // per dir: B blocked [b][1024][16][4] then C blocked
#define WT_OFF   BC_OFF                     // wT_out[256][128]; BC dead after scan
#define WTIN_OFF DELTA_OFF                  // wT_in[128][512]; delta written later by front

__device__ __forceinline__ float sigmoidf_(float x) { return 1.0f / (1.0f + __expf(-x)); }
__device__ __forceinline__ float siluf_(float x)    { return x * sigmoidf_(x); }
__device__ __forceinline__ float softplusf_(float x){ return (x > 20.0f) ? x : log1pf(__expf(x)); }

// raw v_exp_f32 (computes 2^x); s_nop covers the trans->consumer hazard.
__device__ __forceinline__ float fast_exp2(float x) {
    float r;
    asm volatile("v_exp_f32 %0, %1\n\ts_nop 0" : "=v"(r) : "v"(x));
    return r;
}

// dir permutation: scan-domain index j -> original-domain index
__device__ __forceinline__ int perm_idx(int dir, int j) {
    if (dir == 0) return j;
    if (dir == 1) return 4095 - j;
    return ((j & 15) << 8) | (j >> 4);   // slice: j = jj*16+s -> s*256+jj
}

// DPP cross-lane move (VALU pipe, no LDS). ctrl must be a literal.
#define DPP_MOV(x, ctrl) __int_as_float(__builtin_amdgcn_update_dpp(0, __float_as_int(x), (ctrl), 0xF, 0xF, true))
// 16-lane butterfly sum via DPP.
__device__ __forceinline__ float dpp_sum16(float x) {
    x += DPP_MOV(x, 0xB1);    // quad_perm [1,0,3,2]
    x += DPP_MOV(x, 0x4E);    // quad_perm [2,3,0,1]
    x += DPP_MOV(x, 0x141);   // row_half_mirror
    x += DPP_MOV(x, 0x140);   // row_mirror
    return x;
}

// ---------------------------------------------------------------------------
// K0: wT_in[c][p] = in_proj_w[p][c]   (128 x 512)
__global__ __launch_bounds__(256) void transpose_in_kernel(const float* __restrict__ w,
                                                           float* __restrict__ wT) {
    int idx = blockIdx.x * 256 + threadIdx.x;   // 65536
    int p = idx >> 7, c = idx & 127;
    wT[(size_t)c * 512 + p] = w[(size_t)p * 128 + c];
}

// ---------------------------------------------------------------------------
// K1: xz[b][p][l] = sum_c wT_in[c][p] * x_in[b][l][c]
// grid(256, 4), block 256: 16-l tile; thread = 4p x 8l register block.
__global__ __launch_bounds__(256) void inproj_kernel(const float* __restrict__ x,
                              const float* __restrict__ wT,
                              float* __restrict__ xz) {
    const int b = blockIdx.y;
    const int l0 = blockIdx.x * 16;
    __shared__ float xs[128 * 20];   // [c][l], stride 20 (16B-mult, small write conflicts ok)
    for (int idx = threadIdx.x; idx < 16 * 128; idx += 256) {
        int li = idx >> 7, c = idx & 127;
        xs[c * 20 + li] = x[((size_t)(b * 4096 + l0 + li)) * 128 + c];
    }
    __syncthreads();
    const int p0 = (threadIdx.x & 127) * 4;
    const int g8 = (threadIdx.x >> 7) * 8;    // l-subtile 0 or 8
    float acc[4][8];
    #pragma unroll
    for (int j = 0; j < 4; ++j)
        #pragma unroll
        for (int k = 0; k < 8; ++k) acc[j][k] = 0.0f;
    for (int c = 0; c < 128; ++c) {
        float4 wv = *(const float4*)(wT + (size_t)c * 512 + p0);
        const float* xp = xs + c * 20 + g8;
        float4 x0 = *(const float4*)(xp);
        float4 x1 = *(const float4*)(xp + 4);
        float xv[8] = {x0.x, x0.y, x0.z, x0.w, x1.x, x1.y, x1.z, x1.w};
        float wj[4] = {wv.x, wv.y, wv.z, wv.w};
        #pragma unroll
        for (int j = 0; j < 4; ++j)
            #pragma unroll
            for (int k = 0; k < 8; ++k) acc[j][k] += wj[j] * xv[k];
    }
    #pragma unroll
    for (int j = 0; j < 4; ++j) {
        float* op = xz + ((size_t)(b * 512 + p0 + j)) * 4096 + l0 + g8;
        float4 s0; s0.x = acc[j][0]; s0.y = acc[j][1]; s0.z = acc[j][2]; s0.w = acc[j][3];
        float4 s1; s1.x = acc[j][4]; s1.y = acc[j][5]; s1.z = acc[j][6]; s1.w = acc[j][7];
        *(float4*)(op) = s0; *(float4*)(op + 4) = s1;
    }
}

// ---------------------------------------------------------------------------
// K2a: dir2 conv+silu via in-LDS row transpose. Block = one (b,d) row.
__global__ __launch_bounds__(256) void conv2_kernel(const float* __restrict__ ws_xz,
                                 float* __restrict__ ws_u2,
                                 const float* __restrict__ cw2, const float* __restrict__ cb2) {
    const int d = blockIdx.x, b = blockIdx.y;
    const float* xrow = ws_xz + ((size_t)(b * 512 + d)) * 4096;
    float* urow = ws_u2 + ((size_t)(b * 256 + d)) * 4096;
    __shared__ float sh[16 * 260];   // sh[s][jj], pad 260
    for (int i = threadIdx.x; i < 4096; i += 256)
        sh[(i >> 8) * 260 + (i & 255)] = xrow[i];
    __syncthreads();
    const float w0 = cw2[d * 4 + 0], w1 = cw2[d * 4 + 1], w2 = cw2[d * 4 + 2], w3 = cw2[d * 4 + 3];
    const float bb = cb2[d];
    const int t = threadIdx.x;       // j = 16t .. 16t+15
    float xwin[19];
    #pragma unroll
    for (int k = 0; k < 19; ++k) {
        int j = 16 * t - 3 + k;
        xwin[k] = (j >= 0) ? sh[(j & 15) * 260 + (j >> 4)] : 0.0f;
    }
    float r[16];
    #pragma unroll
    for (int i = 0; i < 16; ++i)
        r[i] = siluf_(bb + w0 * xwin[i] + w1 * xwin[i + 1] + w2 * xwin[i + 2] + w3 * xwin[i + 3]);
    #pragma unroll
    for (int q = 0; q < 4; ++q) {
        float4 v; v.x = r[q*4]; v.y = r[q*4+1]; v.z = r[q*4+2]; v.w = r[q*4+3];
        *(float4*)(urow + 16 * t + q * 4) = v;
    }
}

// ---------------------------------------------------------------------------
// K2b (fused conv+silu+x_proj+dt): per (32-l tile, b, dir).
__global__ __launch_bounds__(256) void front_kernel(float* __restrict__ ws,
        const float* __restrict__ xw0, const float* __restrict__ xw1, const float* __restrict__ xw2,
        const float* __restrict__ dw0, const float* __restrict__ dw1, const float* __restrict__ dw2,
        const float* __restrict__ db0, const float* __restrict__ db1, const float* __restrict__ db2,
        const float* __restrict__ cw0, const float* __restrict__ cb0,
        const float* __restrict__ cw1, const float* __restrict__ cb1) {
    const int l0 = blockIdx.x * 32, b = blockIdx.y, dir = blockIdx.z;
    const float* xw = (dir == 0) ? xw0 : (dir == 1) ? xw1 : xw2;
    const float* dw = (dir == 0) ? dw0 : (dir == 1) ? dw1 : dw2;
    const float* db = (dir == 0) ? db0 : (dir == 1) ? db1 : db2;
    const float* xzb = ws + XZ_OFF + (size_t)b * 512 * 4096;
    float* ub      = ws + U_OFF + (size_t)dir * DIR_SZ + (size_t)b * 256 * 4096;
    float* deltab  = ws + DELTA_OFF + (size_t)dir * DIR_SZ + (size_t)b * 256 * 4096;
    float* Bf      = ws + BC_OFF + (size_t)dir * BC_SZ;
    float* Cf      = Bf + BC_SZ / 2;

    __shared__ float xt[256 * 41];   // staging rows [d][k], stride 41
    __shared__ float xd[40 * 33];
    float* ut = xt;                  // reused after conv: [li][264] swizzled

    const int d = threadIdx.x;
    float r[32];

    if (dir != 2) {
        const float* cw = (dir == 0) ? cw0 : cw1;
        const float* cb = (dir == 0) ? cb0 : cb1;
        for (int idx = threadIdx.x; idx < 256 * 35; idx += 256) {
            int dd = idx / 35, k = idx - dd * 35;
            int j = l0 - 3 + k;
            float v = 0.0f;
            if (j >= 0) v = xzb[(size_t)dd * 4096 + ((dir == 1) ? (4095 - j) : j)];
            xt[dd * 41 + k] = v;
        }
        __syncthreads();
        const float w0 = cw[d * 4 + 0], w1 = cw[d * 4 + 1], w2 = cw[d * 4 + 2], w3 = cw[d * 4 + 3];
        const float bb = cb[d];
        float win[35];
        #pragma unroll
        for (int k = 0; k < 35; ++k) win[k] = xt[d * 41 + k];
        #pragma unroll
        for (int li = 0; li < 32; ++li)
            r[li] = siluf_(bb + w0 * win[li] + w1 * win[li + 1] + w2 * win[li + 2] + w3 * win[li + 3]);
        float* urow = ub + (size_t)d * 4096 + l0;
        #pragma unroll
        for (int q = 0; q < 8; ++q) {
            float4 v; v.x = r[q*4]; v.y = r[q*4+1]; v.z = r[q*4+2]; v.w = r[q*4+3];
            *(float4*)(urow + q * 4) = v;
        }
        __syncthreads();
    } else {
        const float* urow = ub + (size_t)d * 4096 + l0;
        #pragma unroll
        for (int q = 0; q < 8; ++q) {
            float4 v = *(const float4*)(urow + q * 4);
            r[q*4] = v.x; r[q*4+1] = v.y; r[q*4+2] = v.z; r[q*4+3] = v.w;
        }
        __syncthreads();
    }

    // store u-tile swizzled: ut[li][ 4*((d>>2)^(li&7)) + (d&3) ]
    #pragma unroll
    for (int li = 0; li < 32; ++li)
        ut[li * 264 + 4 * (((d >> 2) ^ (li & 7))) + (d & 3)] = r[li];
    __syncthreads();

    // ---- 40x256 GEMM: xd[40][32] = xw @ u-tile
    {
        const int rg = threadIdx.x >> 5;
        const int li = threadIdx.x & 31;
        float acc[5];
        #pragma unroll
        for (int j = 0; j < 5; ++j) acc[j] = 0.0f;
        const float* up = ut + li * 264;
        const int sw = (li & 7);
        #pragma unroll 2
        for (int c4 = 0; c4 < 64; ++c4) {
            float4 uv = *(const float4*)(up + 4 * (c4 ^ sw));
            const int c = 4 * (c4 ^ sw);
            #pragma unroll
            for (int j = 0; j < 5; ++j) {
                float4 wv = *(const float4*)(xw + (size_t)(rg * 5 + j) * 256 + c);
                acc[j] += wv.x * uv.x + wv.y * uv.y + wv.z * uv.z + wv.w * uv.w;
            }
        }
        #pragma unroll
        for (int j = 0; j < 5; ++j) xd[(rg * 5 + j) * 33 + li] = acc[j];
    }
    __syncthreads();

    // ---- B/C blocked writes (wave-coalesced) + delta
    {
        const int wv = threadIdx.x >> 6;
        const int lane = threadIdx.x & 63;
        const int n = lane >> 2, lq = lane & 3;
        #pragma unroll
        for (int j = 0; j < 2; ++j) {
            int l4 = (l0 >> 2) + j * 4 + wv;
            int li = (j * 4 + wv) * 4 + lq;
            size_t base = (((size_t)b * 1024 + l4) * 16 + n) * 4 + lq;
            Bf[base] = xd[(8 + n) * 33 + li];
            Cf[base] = xd[(24 + n) * 33 + li];
        }
    }
    {
        const int li = threadIdx.x & 31;
        float xr8[8];
        #pragma unroll
        for (int rr = 0; rr < 8; ++rr) xr8[rr] = xd[rr * 33 + li];
        #pragma unroll
        for (int k = 0; k < 32; ++k) {
            int dd = ((threadIdx.x + k * 256) >> 5);
            float4 wa = *(const float4*)(dw + dd * 8);
            float4 wb = *(const float4*)(dw + dd * 8 + 4);
            float acc = db[dd]
                + wa.x * xr8[0] + wa.y * xr8[1] + wa.z * xr8[2] + wa.w * xr8[3]
                + wb.x * xr8[4] + wb.y * xr8[5] + wb.z * xr8[6] + wb.w * xr8[7];
            deltab[(size_t)dd * 4096 + l0 + li] = softplusf_(acc);
        }
    }
}

// ---------------------------------------------------------------------------
// K3: chunked selective scan. Block = (b,d,dir) row: 512 thr = 32 chunks x 16 states.
__global__ __launch_bounds__(512) void scan_kernel(float* __restrict__ ws,
                            const float* __restrict__ Al0, const float* __restrict__ Dp0,
                            const float* __restrict__ Al1, const float* __restrict__ Dp1,
                            const float* __restrict__ Al2, const float* __restrict__ Dp2) {
    const int d = blockIdx.x, b = blockIdx.y, dir = blockIdx.z;
    const float* Al = (dir == 0) ? Al0 : (dir == 1) ? Al1 : Al2;
    const float* Dp = (dir == 0) ? Dp0 : (dir == 1) ? Dp1 : Dp2;
    const int c = threadIdx.x >> 4;     // chunk 0..31
    const int n = threadIdx.x & 15;     // state 0..15
    const float Ane = -1.44269504f * __expf(Al[d * 16 + n]);   // log2e folded: exp(An*x)=2^(Ane*x)
    const float Dd = Dp[d];
    const float* urow = ws + U_OFF + (size_t)dir * DIR_SZ + ((size_t)(b * 256 + d)) * 4096;
    float* drow = ws + DELTA_OFF + (size_t)dir * DIR_SZ + ((size_t)(b * 256 + d)) * 4096;

    __shared__ float sdu[32 * 264];     // [chunk][(dv,du) x128 + pad]
    __shared__ float Ssh[32 * 16];
    __shared__ float Psh[32 * 16];

    {
        const float4* d4 = (const float4*)drow;
        const float4* u4 = (const float4*)urow;
        for (int i = threadIdx.x; i < 1024; i += 512) {
            float4 dv = d4[i], uv = u4[i];
            int l = i * 4;
            float* p = sdu + (l >> 7) * 264 + (l & 127) * 2;
            float4 a, bq;
            a.x = dv.x; a.y = dv.x * uv.x; a.z = dv.y; a.w = dv.y * uv.y;
            bq.x = dv.z; bq.y = dv.z * uv.z; bq.z = dv.w; bq.w = dv.w * uv.w;
            *(float4*)(p) = a; *(float4*)(p + 4) = bq;
        }
    }
    __syncthreads();

    const float4* Bq = (const float4*)(ws + BC_OFF + (size_t)dir * BC_SZ)
                       + ((size_t)b * 1024 + c * 32) * 16 + n;
    const float4* Cq = (const float4*)(ws + BC_OFF + (size_t)dir * BC_SZ + BC_SZ / 2)
                       + ((size_t)b * 1024 + c * 32) * 16 + n;
    const float4* sp = (const float4*)(sdu + c * 264);

    // ownership masks: msk[m] = (n==m) ? 1 : 0
    float msk[16];
    #pragma unroll
    for (int m = 0; m < 16; ++m) msk[m] = (n == m) ? 1.0f : 0.0f;

    // Pass 1: local scan + decay-sum
    float S = 0.0f, dsum = 0.0f;
    #pragma unroll 8
    for (int k4 = 0; k4 < 32; ++k4) {
        float4 a = sp[k4 * 2], bq = sp[k4 * 2 + 1];
        float4 Bv = Bq[(size_t)k4 * 16];
        dsum += a.x + a.z + bq.x + bq.z;
        S = S * fast_exp2(Ane * a.x) + a.y * Bv.x;
        S = S * fast_exp2(Ane * a.z) + a.w * Bv.y;
        S = S * fast_exp2(Ane * bq.x) + bq.y * Bv.z;
        S = S * fast_exp2(Ane * bq.z) + bq.w * Bv.w;
    }
    Ssh[c * 16 + n] = S;
    Psh[c * 16 + n] = fast_exp2(Ane * dsum);
    __syncthreads();
    float h = 0.0f;
    for (int k = 0; k < c; ++k) h = h * Psh[k * 16 + n] + Ssh[k * 16 + n];

    // Pass 2: rescan, produce y (groups of 16 steps; lane keeps local step == n)
    for (int g = 0; g < 8; ++g) {
        float uown = urow[c * 128 + g * 16 + n];
        float yv = 0.0f;
        #pragma unroll
        for (int k4 = 0; k4 < 4; ++k4) {
            float4 a = sp[g * 8 + k4 * 2], bq = sp[g * 8 + k4 * 2 + 1];
            float4 Bv = Bq[(size_t)(g * 4 + k4) * 16];
            float4 Cv = Cq[(size_t)(g * 4 + k4) * 16];
            #pragma unroll
            for (int j = 0; j < 4; ++j) {
                float dv = (j == 0) ? a.x : (j == 1) ? a.z : (j == 2) ? bq.x : bq.z;
                float du = (j == 0) ? a.y : (j == 1) ? a.w : (j == 2) ? bq.y : bq.w;
                float Bn = (j == 0) ? Bv.x : (j == 1) ? Bv.y : (j == 2) ? Bv.z : Bv.w;
                float Cn = (j == 0) ? Cv.x : (j == 1) ? Cv.y : (j == 2) ? Cv.z : Cv.w;
                h = h * fast_exp2(Ane * dv) + du * Bn;
                float yp = dpp_sum16(h * Cn);
                yv = fmaf(msk[k4 * 4 + j], yp, yv);   // ownership select as FMA
            }
        }
        int gl = c * 128 + g * 16 + n;
        drow[perm_idx(dir, gl)] = yv + Dd * uown;
    }
}

// ---------------------------------------------------------------------------
// K3b: wT_out[d][o] = out_proj_w[o][d]  (after scan; reuses dead BC region)
__global__ __launch_bounds__(256) void transpose_w_kernel(const float* __restrict__ ow,
                                                          float* __restrict__ wT) {
    int idx = blockIdx.x * 256 + threadIdx.x;   // 32768
    int d = idx >> 7, o = idx & 127;
    wT[d * 128 + o] = ow[o * 256 + d];
}

// ---------------------------------------------------------------------------
// K4: y_total = silu(z)*(yf+yb+ys); out = wT^T @ y_total.
__global__ __launch_bounds__(256) void epilogue_kernel(const float* __restrict__ ws,
                                const float* __restrict__ wT,
                                float* __restrict__ out) {
    const int l0 = blockIdx.x * 32, b = blockIdx.y;
    __shared__ float yt[256][36];
    const float* yf = ws + DELTA_OFF;
    const float* yb = ws + DELTA_OFF + DIR_SZ;
    const float* ysd = ws + DELTA_OFF + 2 * DIR_SZ;

    for (int idx = threadIdx.x; idx < 256 * 32; idx += 256) {
        int d = idx >> 5, li = idx & 31;
        int l = l0 + li;
        size_t ro = ((size_t)(b * 256 + d)) * 4096 + l;
        float z  = ws[XZ_OFF + ((size_t)(b * 512 + 256 + d)) * 4096 + l];
        yt[d][li] = (yf[ro] + yb[ro] + ysd[ro]) * siluf_(z);
    }
    __syncthreads();

    const int o0  = (threadIdx.x & 63) * 2;
    const int li0 = (threadIdx.x >> 6) * 8;
    float accA[8], accB[8];
    #pragma unroll
    for (int k = 0; k < 8; ++k) { accA[k] = 0.0f; accB[k] = 0.0f; }
    for (int d = 0; d < 256; ++d) {
        float2 wv = *(const float2*)(wT + d * 128 + o0);
        float4 y0 = *(const float4*)(&yt[d][li0]);
        float4 y1 = *(const float4*)(&yt[d][li0 + 4]);
        accA[0] += wv.x * y0.x; accA[1] += wv.x * y0.y; accA[2] += wv.x * y0.z; accA[3] += wv.x * y0.w;
        accA[4] += wv.x * y1.x; accA[5] += wv.x * y1.y; accA[6] += wv.x * y1.z; accA[7] += wv.x * y1.w;
        accB[0] += wv.y * y0.x; accB[1] += wv.y * y0.y; accB[2] += wv.y * y0.z; accB[3] += wv.y * y0.w;
        accB[4] += wv.y * y1.x; accB[5] += wv.y * y1.y; accB[6] += wv.y * y1.z; accB[7] += wv.y * y1.w;
    }
    #pragma unroll
    for (int k = 0; k < 8; ++k) {
        float2 st; st.x = accA[k]; st.y = accB[k];
        *(float2*)(out + ((size_t)(b * 4096 + l0 + li0 + k)) * 128 + o0) = st;
    }
}

// ---------------------------------------------------------------------------
extern "C" void kernel_launch(void* const* d_in, const int* in_sizes, int n_in,
                              void* d_out, int out_size, void* d_ws, size_t ws_size,
                              hipStream_t stream) {
    const float* x_in = (const float*)d_in[0];
    const float* ipw  = (const float*)d_in[1];
    const float* cw[3]  = {(const float*)d_in[2],  (const float*)d_in[9],  (const float*)d_in[16]};
    const float* cb[3]  = {(const float*)d_in[3],  (const float*)d_in[10], (const float*)d_in[17]};
    const float* xpw[3] = {(const float*)d_in[4],  (const float*)d_in[11], (const float*)d_in[18]};
    const float* dtw[3] = {(const float*)d_in[5],  (const float*)d_in[12], (const float*)d_in[19]};
    const float* dtb[3] = {(const float*)d_in[6],  (const float*)d_in[13], (const float*)d_in[20]};
    const float* alog[3]= {(const float*)d_in[7],  (const float*)d_in[14], (const float*)d_in[21]};
    const float* dp[3]  = {(const float*)d_in[8],  (const float*)d_in[15], (const float*)d_in[22]};
    const float* ow   = (const float*)d_in[23];
    float* ws  = (float*)d_ws;
    float* out = (float*)d_out;

    transpose_in_kernel<<<dim3(256), 256, 0, stream>>>(ipw, ws + WTIN_OFF);
    inproj_kernel<<<dim3(256, 4), 256, 0, stream>>>(x_in, ws + WTIN_OFF, ws);
    conv2_kernel<<<dim3(256, 4), 256, 0, stream>>>(ws, ws + U_OFF + 2 * DIR_SZ, cw[2], cb[2]);
    front_kernel<<<dim3(128, 4, 3), 256, 0, stream>>>(ws,
        xpw[0], xpw[1], xpw[2], dtw[0], dtw[1], dtw[2], dtb[0], dtb[1], dtb[2],
        cw[0], cb[0], cw[1], cb[1]);
    scan_kernel<<<dim3(256, 4, 3), 512, 0, stream>>>(ws,
        alog[0], dp[0], alog[1], dp[1], alog[2], dp[2]);
    transpose_w_kernel<<<dim3(128), 256, 0, stream>>>(ow, ws + WT_OFF);
    epilogue_kernel<<<dim3(128, 4), 256, 0, stream>>>(ws, ws + WT_OFF, out);
}

// Round 6
// 432.297 us; speedup vs baseline: 6.5558x; 1.0333x over previous
//
#include <hip/hip_runtime.h>
#include <math.h>

// Problem constants
// B=4, H=W=64 -> L=4096, DIM=128, D_INNER=256, D_STATE=16, D_CONV=4, DT_RANK=8, NSLICES=16
#define LSEQ 4096

// Workspace layout (floats). Total ~134 MB (proven to fit)
#define XZ_OFF   0ULL
#define XZ_SZ    (4ULL * 512 * 4096)        // xz[b][p][l], l-contiguous
#define U_OFF    (XZ_OFF + XZ_SZ)
#define DIR_SZ   (4ULL * 256 * 4096)        // per direction
#define DELTA_OFF (U_OFF + 3ULL * DIR_SZ)   // delta; also holds wT_in before front runs
#define BC_OFF   (DELTA_OFF + 3ULL * DIR_SZ)
#define BC_SZ    (4ULL * 4096 * 32)         // per dir: B blocked [b][1024][16][4] then C blocked
#define WT_OFF   BC_OFF                     // wT_out[256][128]; BC dead after scan
#define WTIN_OFF DELTA_OFF                  // wT_in[128][512]; delta written later by front

__device__ __forceinline__ float sigmoidf_(float x) { return 1.0f / (1.0f + __expf(-x)); }
__device__ __forceinline__ float siluf_(float x)    { return x * sigmoidf_(x); }
__device__ __forceinline__ float softplusf_(float x){ return (x > 20.0f) ? x : log1pf(__expf(x)); }

// raw v_exp_f32 (computes 2^x); s_nop covers the trans->consumer hazard.
__device__ __forceinline__ float fast_exp2(float x) {
    float r;
    asm volatile("v_exp_f32 %0, %1\n\ts_nop 0" : "=v"(r) : "v"(x));
    return r;
}

// dir permutation: scan-domain index j -> original-domain index
__device__ __forceinline__ int perm_idx(int dir, int j) {
    if (dir == 0) return j;
    if (dir == 1) return 4095 - j;
    return ((j & 15) << 8) | (j >> 4);   // slice: j = jj*16+s -> s*256+jj
}

// DPP cross-lane move (VALU pipe, no LDS). ctrl must be a literal.
#define DPP_MOV(x, ctrl) __int_as_float(__builtin_amdgcn_update_dpp(0, __float_as_int(x), (ctrl), 0xF, 0xF, true))

// ---------------------------------------------------------------------------
// K0: wT_in[c][p] = in_proj_w[p][c]   (128 x 512)
__global__ __launch_bounds__(256) void transpose_in_kernel(const float* __restrict__ w,
                                                           float* __restrict__ wT) {
    int idx = blockIdx.x * 256 + threadIdx.x;   // 65536
    int p = idx >> 7, c = idx & 127;
    wT[(size_t)c * 512 + p] = w[(size_t)p * 128 + c];
}

// ---------------------------------------------------------------------------
// K1: xz[b][p][l] = sum_c wT_in[c][p] * x_in[b][l][c]
__global__ __launch_bounds__(256) void inproj_kernel(const float* __restrict__ x,
                              const float* __restrict__ wT,
                              float* __restrict__ xz) {
    const int b = blockIdx.y;
    const int l0 = blockIdx.x * 16;
    __shared__ float xs[128 * 20];   // [c][l]
    for (int idx = threadIdx.x; idx < 16 * 128; idx += 256) {
        int li = idx >> 7, c = idx & 127;
        xs[c * 20 + li] = x[((size_t)(b * 4096 + l0 + li)) * 128 + c];
    }
    __syncthreads();
    const int p0 = (threadIdx.x & 127) * 4;
    const int g8 = (threadIdx.x >> 7) * 8;
    float acc[4][8];
    #pragma unroll
    for (int j = 0; j < 4; ++j)
        #pragma unroll
        for (int k = 0; k < 8; ++k) acc[j][k] = 0.0f;
    for (int c = 0; c < 128; ++c) {
        float4 wv = *(const float4*)(wT + (size_t)c * 512 + p0);
        const float* xp = xs + c * 20 + g8;
        float4 x0 = *(const float4*)(xp);
        float4 x1 = *(const float4*)(xp + 4);
        float xv[8] = {x0.x, x0.y, x0.z, x0.w, x1.x, x1.y, x1.z, x1.w};
        float wj[4] = {wv.x, wv.y, wv.z, wv.w};
        #pragma unroll
        for (int j = 0; j < 4; ++j)
            #pragma unroll
            for (int k = 0; k < 8; ++k) acc[j][k] += wj[j] * xv[k];
    }
    #pragma unroll
    for (int j = 0; j < 4; ++j) {
        float* op = xz + ((size_t)(b * 512 + p0 + j)) * 4096 + l0 + g8;
        float4 s0; s0.x = acc[j][0]; s0.y = acc[j][1]; s0.z = acc[j][2]; s0.w = acc[j][3];
        float4 s1; s1.x = acc[j][4]; s1.y = acc[j][5]; s1.z = acc[j][6]; s1.w = acc[j][7];
        *(float4*)(op) = s0; *(float4*)(op + 4) = s1;
    }
}

// ---------------------------------------------------------------------------
// K2a: dir2 conv+silu via in-LDS row transpose. Block = one (b,d) row.
__global__ __launch_bounds__(256) void conv2_kernel(const float* __restrict__ ws_xz,
                                 float* __restrict__ ws_u2,
                                 const float* __restrict__ cw2, const float* __restrict__ cb2) {
    const int d = blockIdx.x, b = blockIdx.y;
    const float* xrow = ws_xz + ((size_t)(b * 512 + d)) * 4096;
    float* urow = ws_u2 + ((size_t)(b * 256 + d)) * 4096;
    __shared__ float sh[16 * 260];
    for (int i = threadIdx.x; i < 4096; i += 256)
        sh[(i >> 8) * 260 + (i & 255)] = xrow[i];
    __syncthreads();
    const float w0 = cw2[d * 4 + 0], w1 = cw2[d * 4 + 1], w2 = cw2[d * 4 + 2], w3 = cw2[d * 4 + 3];
    const float bb = cb2[d];
    const int t = threadIdx.x;
    float xwin[19];
    #pragma unroll
    for (int k = 0; k < 19; ++k) {
        int j = 16 * t - 3 + k;
        xwin[k] = (j >= 0) ? sh[(j & 15) * 260 + (j >> 4)] : 0.0f;
    }
    float r[16];
    #pragma unroll
    for (int i = 0; i < 16; ++i)
        r[i] = siluf_(bb + w0 * xwin[i] + w1 * xwin[i + 1] + w2 * xwin[i + 2] + w3 * xwin[i + 3]);
    #pragma unroll
    for (int q = 0; q < 4; ++q) {
        float4 v; v.x = r[q*4]; v.y = r[q*4+1]; v.z = r[q*4+2]; v.w = r[q*4+3];
        *(float4*)(urow + 16 * t + q * 4) = v;
    }
}

// ---------------------------------------------------------------------------
// K2b (fused conv+silu+x_proj+dt): per (32-l tile, b, dir).
// Phase A staging now vectorized: 9 aligned float4 loads/thread; window k = j-(l0-4).
__global__ __launch_bounds__(256) void front_kernel(float* __restrict__ ws,
        const float* __restrict__ xw0, const float* __restrict__ xw1, const float* __restrict__ xw2,
        const float* __restrict__ dw0, const float* __restrict__ dw1, const float* __restrict__ dw2,
        const float* __restrict__ db0, const float* __restrict__ db1, const float* __restrict__ db2,
        const float* __restrict__ cw0, const float* __restrict__ cb0,
        const float* __restrict__ cw1, const float* __restrict__ cb1) {
    const int l0 = blockIdx.x * 32, b = blockIdx.y, dir = blockIdx.z;
    const float* xw = (dir == 0) ? xw0 : (dir == 1) ? xw1 : xw2;
    const float* dw = (dir == 0) ? dw0 : (dir == 1) ? dw1 : dw2;
    const float* db = (dir == 0) ? db0 : (dir == 1) ? db1 : db2;
    const float* xzb = ws + XZ_OFF + (size_t)b * 512 * 4096;
    float* ub      = ws + U_OFF + (size_t)dir * DIR_SZ + (size_t)b * 256 * 4096;
    float* deltab  = ws + DELTA_OFF + (size_t)dir * DIR_SZ + (size_t)b * 256 * 4096;
    float* Bf      = ws + BC_OFF + (size_t)dir * BC_SZ;
    float* Cf      = Bf + BC_SZ / 2;

    __shared__ float xt[256 * 41];   // staging rows [d][k], k=0..35, stride 41
    __shared__ float xd[40 * 33];
    float* ut = xt;                  // reused after conv: [li][264] swizzled

    const int d = threadIdx.x;
    float r[32];

    if (dir != 2) {
        const float* cw = (dir == 0) ? cw0 : cw1;
        const float* cb = (dir == 0) ? cb0 : cb1;
        // stage window as aligned float4s: k=4i..4i+3 maps to j=l0-4+4i..+3
        for (int idx = threadIdx.x; idx < 256 * 9; idx += 256) {
            int dd = idx / 9, i4 = idx - dd * 9;
            int jb = l0 - 4 + i4 * 4;            // aligned base, mult of 4
            float v0 = 0.f, v1 = 0.f, v2 = 0.f, v3 = 0.f;
            if (jb >= 0) {
                if (dir == 0) {
                    float4 v = *(const float4*)(xzb + (size_t)dd * 4096 + jb);
                    v0 = v.x; v1 = v.y; v2 = v.z; v3 = v.w;
                } else {
                    float4 v = *(const float4*)(xzb + (size_t)dd * 4096 + (4092 - jb));
                    v0 = v.w; v1 = v.z; v2 = v.y; v3 = v.x;   // reversed
                }
            }
            float* xr = xt + dd * 41 + i4 * 4;
            xr[0] = v0; xr[1] = v1; xr[2] = v2; xr[3] = v3;
        }
        __syncthreads();
        const float w0 = cw[d * 4 + 0], w1 = cw[d * 4 + 1], w2 = cw[d * 4 + 2], w3 = cw[d * 4 + 3];
        const float bb = cb[d];
        float win[36];
        #pragma unroll
        for (int k = 0; k < 36; ++k) win[k] = xt[d * 41 + k];
        #pragma unroll
        for (int li = 0; li < 32; ++li)
            r[li] = siluf_(bb + w0 * win[li + 1] + w1 * win[li + 2] + w2 * win[li + 3] + w3 * win[li + 4]);
        float* urow = ub + (size_t)d * 4096 + l0;
        #pragma unroll
        for (int q = 0; q < 8; ++q) {
            float4 v; v.x = r[q*4]; v.y = r[q*4+1]; v.z = r[q*4+2]; v.w = r[q*4+3];
            *(float4*)(urow + q * 4) = v;
        }
        __syncthreads();
    } else {
        const float* urow = ub + (size_t)d * 4096 + l0;
        #pragma unroll
        for (int q = 0; q < 8; ++q) {
            float4 v = *(const float4*)(urow + q * 4);
            r[q*4] = v.x; r[q*4+1] = v.y; r[q*4+2] = v.z; r[q*4+3] = v.w;
        }
        __syncthreads();
    }

    #pragma unroll
    for (int li = 0; li < 32; ++li)
        ut[li * 264 + 4 * (((d >> 2) ^ (li & 7))) + (d & 3)] = r[li];
    __syncthreads();

    // ---- 40x256 GEMM: xd[40][32] = xw @ u-tile
    {
        const int rg = threadIdx.x >> 5;
        const int li = threadIdx.x & 31;
        float acc[5];
        #pragma unroll
        for (int j = 0; j < 5; ++j) acc[j] = 0.0f;
        const float* up = ut + li * 264;
        const int sw = (li & 7);
        #pragma unroll 2
        for (int c4 = 0; c4 < 64; ++c4) {
            float4 uv = *(const float4*)(up + 4 * (c4 ^ sw));
            const int c = 4 * (c4 ^ sw);
            #pragma unroll
            for (int j = 0; j < 5; ++j) {
                float4 wv = *(const float4*)(xw + (size_t)(rg * 5 + j) * 256 + c);
                acc[j] += wv.x * uv.x + wv.y * uv.y + wv.z * uv.z + wv.w * uv.w;
            }
        }
        #pragma unroll
        for (int j = 0; j < 5; ++j) xd[(rg * 5 + j) * 33 + li] = acc[j];
    }
    __syncthreads();

    // ---- B/C blocked writes (wave-coalesced) + delta
    {
        const int wv = threadIdx.x >> 6;
        const int lane = threadIdx.x & 63;
        const int n = lane >> 2, lq = lane & 3;
        #pragma unroll
        for (int j = 0; j < 2; ++j) {
            int l4 = (l0 >> 2) + j * 4 + wv;
            int li = (j * 4 + wv) * 4 + lq;
            size_t base = (((size_t)b * 1024 + l4) * 16 + n) * 4 + lq;
            Bf[base] = xd[(8 + n) * 33 + li];
            Cf[base] = xd[(24 + n) * 33 + li];
        }
    }
    {
        const int li = threadIdx.x & 31;
        float xr8[8];
        #pragma unroll
        for (int rr = 0; rr < 8; ++rr) xr8[rr] = xd[rr * 33 + li];
        #pragma unroll
        for (int k = 0; k < 32; ++k) {
            int dd = ((threadIdx.x + k * 256) >> 5);
            float4 wa = *(const float4*)(dw + dd * 8);
            float4 wb = *(const float4*)(dw + dd * 8 + 4);
            float acc = db[dd]
                + wa.x * xr8[0] + wa.y * xr8[1] + wa.z * xr8[2] + wa.w * xr8[3]
                + wb.x * xr8[4] + wb.y * xr8[5] + wb.z * xr8[6] + wb.w * xr8[7];
            deltab[(size_t)dd * 4096 + l0 + li] = softplusf_(acc);
        }
    }
}

// ---------------------------------------------------------------------------
// K3: chunked selective scan. Block = (b,d,dir) row: 512 thr = 32 chunks x 16 states.
// Pass 2 reduction: 2 DPP quad stages + tiny LDS matrix (mat[4t+quad][chunk], stride 34),
// harvested every 8 steps (4 b32 reads + 3 adds). mat unions with Psh/Ssh region.
__global__ __launch_bounds__(512) void scan_kernel(float* __restrict__ ws,
                            const float* __restrict__ Al0, const float* __restrict__ Dp0,
                            const float* __restrict__ Al1, const float* __restrict__ Dp1,
                            const float* __restrict__ Al2, const float* __restrict__ Dp2) {
    const int d = blockIdx.x, b = blockIdx.y, dir = blockIdx.z;
    const float* Al = (dir == 0) ? Al0 : (dir == 1) ? Al1 : Al2;
    const float* Dp = (dir == 0) ? Dp0 : (dir == 1) ? Dp1 : Dp2;
    const int c = threadIdx.x >> 4;     // chunk 0..31
    const int n = threadIdx.x & 15;     // state 0..15
    const int qid = n >> 2;             // quad within chunk
    const float Ane = -1.44269504f * __expf(Al[d * 16 + n]);
    const float Dd = Dp[d];
    const float* urow = ws + U_OFF + (size_t)dir * DIR_SZ + ((size_t)(b * 256 + d)) * 4096;
    float* drow = ws + DELTA_OFF + (size_t)dir * DIR_SZ + ((size_t)(b * 256 + d)) * 4096;

    __shared__ float sdu[32 * 260];     // [chunk][(dv,du) x128 + pad]
    __shared__ float red[32 * 34];      // union: {Psh[512],Ssh[512]} then mat[32][34]
    float* Psh = red;
    float* Ssh = red + 512;

    {
        const float4* d4 = (const float4*)drow;
        const float4* u4 = (const float4*)urow;
        for (int i = threadIdx.x; i < 1024; i += 512) {
            float4 dv = d4[i], uv = u4[i];
            int l = i * 4;
            float* p = sdu + (l >> 7) * 260 + (l & 127) * 2;
            float4 a, bq;
            a.x = dv.x; a.y = dv.x * uv.x; a.z = dv.y; a.w = dv.y * uv.y;
            bq.x = dv.z; bq.y = dv.z * uv.z; bq.z = dv.w; bq.w = dv.w * uv.w;
            *(float4*)(p) = a; *(float4*)(p + 4) = bq;
        }
    }
    __syncthreads();

    const float4* Bq = (const float4*)(ws + BC_OFF + (size_t)dir * BC_SZ)
                       + ((size_t)b * 1024 + c * 32) * 16 + n;
    const float4* Cq = (const float4*)(ws + BC_OFF + (size_t)dir * BC_SZ + BC_SZ / 2)
                       + ((size_t)b * 1024 + c * 32) * 16 + n;
    const float4* sp = (const float4*)(sdu + c * 260);

    // Pass 1: local scan + decay-sum
    float S = 0.0f, dsum = 0.0f;
    #pragma unroll 8
    for (int k4 = 0; k4 < 32; ++k4) {
        float4 a = sp[k4 * 2], bq = sp[k4 * 2 + 1];
        float4 Bv = Bq[(size_t)k4 * 16];
        dsum += a.x + a.z + bq.x + bq.z;
        S = S * fast_exp2(Ane * a.x) + a.y * Bv.x;
        S = S * fast_exp2(Ane * a.z) + a.w * Bv.y;
        S = S * fast_exp2(Ane * bq.x) + bq.y * Bv.z;
        S = S * fast_exp2(Ane * bq.z) + bq.w * Bv.w;
    }
    Ssh[c * 16 + n] = S;
    Psh[c * 16 + n] = fast_exp2(Ane * dsum);
    __syncthreads();
    float h = 0.0f;
    for (int k = 0; k < c; ++k) h = h * Psh[k * 16 + n] + Ssh[k * 16 + n];
    __syncthreads();   // Psh/Ssh fully consumed; red region becomes mat

    // Pass 2: rescan; per step 2 DPP quad stages + 1 LDS write; harvest each 8 steps.
    #define SCAN_STEP(t, dv, du, Bn, Cn) { \
        h = h * fast_exp2(Ane * (dv)) + (du) * (Bn); \
        float yp = h * (Cn); \
        yp += DPP_MOV(yp, 0xB1); \
        yp += DPP_MOV(yp, 0x4E); \
        red[(4 * (t) + qid) * 34 + c] = yp; }

    for (int g = 0; g < 16; ++g) {
        float4 a0 = sp[g * 4 + 0], a1 = sp[g * 4 + 1];
        float4 a2 = sp[g * 4 + 2], a3 = sp[g * 4 + 3];
        float4 Bv0 = Bq[(size_t)(g * 2) * 16], Bv1 = Bq[(size_t)(g * 2 + 1) * 16];
        float4 Cv0 = Cq[(size_t)(g * 2) * 16], Cv1 = Cq[(size_t)(g * 2 + 1) * 16];
        SCAN_STEP(0, a0.x, a0.y, Bv0.x, Cv0.x)
        SCAN_STEP(1, a0.z, a0.w, Bv0.y, Cv0.y)
        SCAN_STEP(2, a1.x, a1.y, Bv0.z, Cv0.z)
        SCAN_STEP(3, a1.z, a1.w, Bv0.w, Cv0.w)
        SCAN_STEP(4, a2.x, a2.y, Bv1.x, Cv1.x)
        SCAN_STEP(5, a2.z, a2.w, Bv1.y, Cv1.y)
        SCAN_STEP(6, a3.x, a3.y, Bv1.z, Cv1.z)
        SCAN_STEP(7, a3.z, a3.w, Bv1.w, Cv1.w)
        // harvest: target t = n&7; Y[t] = sum over 4 quads (same-wave DS ordering)
        const int tt = n & 7;
        float q0 = red[(4 * tt + 0) * 34 + c];
        float q1 = red[(4 * tt + 1) * 34 + c];
        float q2 = red[(4 * tt + 2) * 34 + c];
        float q3 = red[(4 * tt + 3) * 34 + c];
        float y = (q0 + q1) + (q2 + q3);
        if (n < 8) {
            int gl = c * 128 + g * 8 + n;
            drow[perm_idx(dir, gl)] = y + Dd * urow[gl];
        }
    }
    #undef SCAN_STEP
}

// ---------------------------------------------------------------------------
// K3b: wT_out[d][o] = out_proj_w[o][d]  (after scan; reuses dead BC region)
__global__ __launch_bounds__(256) void transpose_w_kernel(const float* __restrict__ ow,
                                                          float* __restrict__ wT) {
    int idx = blockIdx.x * 256 + threadIdx.x;   // 32768
    int d = idx >> 7, o = idx & 127;
    wT[d * 128 + o] = ow[o * 256 + d];
}

// ---------------------------------------------------------------------------
// K4: y_total = silu(z)*(yf+yb+ys); out = wT^T @ y_total.
__global__ __launch_bounds__(256) void epilogue_kernel(const float* __restrict__ ws,
                                const float* __restrict__ wT,
                                float* __restrict__ out) {
    const int l0 = blockIdx.x * 32, b = blockIdx.y;
    __shared__ float yt[256][36];
    const float* yf = ws + DELTA_OFF;
    const float* yb = ws + DELTA_OFF + DIR_SZ;
    const float* ysd = ws + DELTA_OFF + 2 * DIR_SZ;

    for (int idx = threadIdx.x; idx < 256 * 32; idx += 256) {
        int d = idx >> 5, li = idx & 31;
        int l = l0 + li;
        size_t ro = ((size_t)(b * 256 + d)) * 4096 + l;
        float z  = ws[XZ_OFF + ((size_t)(b * 512 + 256 + d)) * 4096 + l];
        yt[d][li] = (yf[ro] + yb[ro] + ysd[ro]) * siluf_(z);
    }
    __syncthreads();

    const int o0  = (threadIdx.x & 63) * 2;
    const int li0 = (threadIdx.x >> 6) * 8;
    float accA[8], accB[8];
    #pragma unroll
    for (int k = 0; k < 8; ++k) { accA[k] = 0.0f; accB[k] = 0.0f; }
    for (int d = 0; d < 256; ++d) {
        float2 wv = *(const float2*)(wT + d * 128 + o0);
        float4 y0 = *(const float4*)(&yt[d][li0]);
        float4 y1 = *(const float4*)(&yt[d][li0 + 4]);
        accA[0] += wv.x * y0.x; accA[1] += wv.x * y0.y; accA[2] += wv.x * y0.z; accA[3] += wv.x * y0.w;
        accA[4] += wv.x * y1.x; accA[5] += wv.x * y1.y; accA[6] += wv.x * y1.z; accA[7] += wv.x * y1.w;
        accB[0] += wv.y * y0.x; accB[1] += wv.y * y0.y; accB[2] += wv.y * y0.z; accB[3] += wv.y * y0.w;
        accB[4] += wv.y * y1.x; accB[5] += wv.y * y1.y; accB[6] += wv.y * y1.z; accB[7] += wv.y * y1.w;
    }
    #pragma unroll
    for (int k = 0; k < 8; ++k) {
        float2 st; st.x = accA[k]; st.y = accB[k];
        *(float2*)(out + ((size_t)(b * 4096 + l0 + li0 + k)) * 128 + o0) = st;
    }
}

// ---------------------------------------------------------------------------
extern "C" void kernel_launch(void* const* d_in, const int* in_sizes, int n_in,
                              void* d_out, int out_size, void* d_ws, size_t ws_size,
                              hipStream_t stream) {
    const float* x_in = (const float*)d_in[0];
    const float* ipw  = (const float*)d_in[1];
    const float* cw[3]  = {(const float*)d_in[2],  (const float*)d_in[9],  (const float*)d_in[16]};
    const float* cb[3]  = {(const float*)d_in[3],  (const float*)d_in[10], (const float*)d_in[17]};
    const float* xpw[3] = {(const float*)d_in[4],  (const float*)d_in[11], (const float*)d_in[18]};
    const float* dtw[3] = {(const float*)d_in[5],  (const float*)d_in[12], (const float*)d_in[19]};
    const float* dtb[3] = {(const float*)d_in[6],  (const float*)d_in[13], (const float*)d_in[20]};
    const float* alog[3]= {(const float*)d_in[7],  (const float*)d_in[14], (const float*)d_in[21]};
    const float* dp[3]  = {(const float*)d_in[8],  (const float*)d_in[15], (const float*)d_in[22]};
    const float* ow   = (const float*)d_in[23];
    float* ws  = (float*)d_ws;
    float* out = (float*)d_out;

    transpose_in_kernel<<<dim3(256), 256, 0, stream>>>(ipw, ws + WTIN_OFF);
    inproj_kernel<<<dim3(256, 4), 256, 0, stream>>>(x_in, ws + WTIN_OFF, ws);
    conv2_kernel<<<dim3(256, 4), 256, 0, stream>>>(ws, ws + U_OFF + 2 * DIR_SZ, cw[2], cb[2]);
    front_kernel<<<dim3(128, 4, 3), 256, 0, stream>>>(ws,
        xpw[0], xpw[1], xpw[2], dtw[0], dtw[1], dtw[2], dtb[0], dtb[1], dtb[2],
        cw[0], cb[0], cw[1], cb[1]);
    scan_kernel<<<dim3(256, 4, 3), 512, 0, stream>>>(ws,
        alog[0], dp[0], alog[1], dp[1], alog[2], dp[2]);
    transpose_w_kernel<<<dim3(128), 256, 0, stream>>>(ow, ws + WT_OFF);
    epilogue_kernel<<<dim3(128, 4), 256, 0, stream>>>(ws, ws + WT_OFF, out);
}

// Round 7
// 426.802 us; speedup vs baseline: 6.6402x; 1.0129x over previous
//
#include <hip/hip_runtime.h>
#include <math.h>

// Problem constants
// B=4, H=W=64 -> L=4096, DIM=128, D_INNER=256, D_STATE=16, D_CONV=4, DT_RANK=8, NSLICES=16
#define LSEQ 4096

// Workspace layout (floats). Total ~134 MB (proven to fit)
// NEW: xz stored [b][l][p] (p-contiguous rows of 512) so conv windows for ALL dirs
// are coalesced row gathers.
#define XZ_OFF   0ULL
#define XZ_SZ    (4ULL * 4096 * 512)
#define U_OFF    (XZ_OFF + XZ_SZ)
#define DIR_SZ   (4ULL * 256 * 4096)        // per direction
#define DELTA_OFF (U_OFF + 3ULL * DIR_SZ)   // delta; also holds wT_in before front runs
#define BC_OFF   (DELTA_OFF + 3ULL * DIR_SZ)
#define BC_SZ    (4ULL * 4096 * 32)         // per dir: B blocked [b][1024][16][4] then C blocked
#define WTIN_OFF DELTA_OFF                  // wT_in[128][512]; delta written later by front

__device__ __forceinline__ float sigmoidf_(float x) { return 1.0f / (1.0f + __expf(-x)); }
__device__ __forceinline__ float siluf_(float x)    { return x * sigmoidf_(x); }
__device__ __forceinline__ float softplusf_(float x){ return (x > 20.0f) ? x : log1pf(__expf(x)); }

// 2^x. Prefer the compiler builtin (it handles the trans-op hazard and can
// schedule/hoist); fall back to asm with explicit s_nop.
__device__ __forceinline__ float fast_exp2_asm(float x) {
    float r;
    asm volatile("v_exp_f32 %0, %1\n\ts_nop 0" : "=v"(r) : "v"(x));
    return r;
}
#if defined(__has_builtin)
#if __has_builtin(__builtin_amdgcn_exp2f)
#define EXP2(x) __builtin_amdgcn_exp2f(x)
#else
#define EXP2(x) fast_exp2_asm(x)
#endif
#else
#define EXP2(x) fast_exp2_asm(x)
#endif

// dir permutation: scan-domain index j -> original-domain index
__device__ __forceinline__ int perm_idx(int dir, int j) {
    if (dir == 0) return j;
    if (dir == 1) return 4095 - j;
    return ((j & 15) << 8) | (j >> 4);   // slice: j = jj*16+s -> s*256+jj
}

// DPP cross-lane move (VALU pipe, no LDS). ctrl must be a literal.
#define DPP_MOV(x, ctrl) __int_as_float(__builtin_amdgcn_update_dpp(0, __float_as_int(x), (ctrl), 0xF, 0xF, true))

// ---------------------------------------------------------------------------
// K0: wT_in[c][p] = in_proj_w[p][c]   (128 x 512)
__global__ __launch_bounds__(256) void transpose_in_kernel(const float* __restrict__ w,
                                                           float* __restrict__ wT) {
    int idx = blockIdx.x * 256 + threadIdx.x;   // 65536
    int p = idx >> 7, c = idx & 127;
    wT[(size_t)c * 512 + p] = w[(size_t)p * 128 + c];
}

// ---------------------------------------------------------------------------
// K1: xz[b][l][p] = sum_c wT_in[c][p] * x_in[b][l][c]   (NEW l-major output)
__global__ __launch_bounds__(256) void inproj_kernel(const float* __restrict__ x,
                              const float* __restrict__ wT,
                              float* __restrict__ xz) {
    const int b = blockIdx.y;
    const int l0 = blockIdx.x * 16;
    __shared__ float xs[128 * 20];   // [c][l]
    for (int idx = threadIdx.x; idx < 16 * 128; idx += 256) {
        int li = idx >> 7, c = idx & 127;
        xs[c * 20 + li] = x[((size_t)(b * 4096 + l0 + li)) * 128 + c];
    }
    __syncthreads();
    const int p0 = (threadIdx.x & 127) * 4;
    const int g8 = (threadIdx.x >> 7) * 8;
    float acc[4][8];
    #pragma unroll
    for (int j = 0; j < 4; ++j)
        #pragma unroll
        for (int k = 0; k < 8; ++k) acc[j][k] = 0.0f;
    for (int c = 0; c < 128; ++c) {
        float4 wv = *(const float4*)(wT + (size_t)c * 512 + p0);
        const float* xp = xs + c * 20 + g8;
        float4 x0 = *(const float4*)(xp);
        float4 x1 = *(const float4*)(xp + 4);
        float xv[8] = {x0.x, x0.y, x0.z, x0.w, x1.x, x1.y, x1.z, x1.w};
        float wj[4] = {wv.x, wv.y, wv.z, wv.w};
        #pragma unroll
        for (int j = 0; j < 4; ++j)
            #pragma unroll
            for (int k = 0; k < 8; ++k) acc[j][k] += wj[j] * xv[k];
    }
    #pragma unroll
    for (int k = 0; k < 8; ++k) {
        float4 s; s.x = acc[0][k]; s.y = acc[1][k]; s.z = acc[2][k]; s.w = acc[3][k];
        *(float4*)(xz + ((size_t)(b * 4096 + l0 + g8 + k)) * 512 + p0) = s;
    }
}

// ---------------------------------------------------------------------------
// K2 (fused conv+silu+x_proj+dt, ALL dirs): per (32-scan-l tile, b, dir).
// Staging = 35 coalesced row reads from xz[b][row][0..255] (row = perm of scan idx).
__global__ __launch_bounds__(256) void front_kernel(float* __restrict__ ws,
        const float* __restrict__ xw0, const float* __restrict__ xw1, const float* __restrict__ xw2,
        const float* __restrict__ dw0, const float* __restrict__ dw1, const float* __restrict__ dw2,
        const float* __restrict__ db0, const float* __restrict__ db1, const float* __restrict__ db2,
        const float* __restrict__ cw0, const float* __restrict__ cb0,
        const float* __restrict__ cw1, const float* __restrict__ cb1,
        const float* __restrict__ cw2, const float* __restrict__ cb2) {
    const int l0 = blockIdx.x * 32, b = blockIdx.y, dir = blockIdx.z;
    const float* xw = (dir == 0) ? xw0 : (dir == 1) ? xw1 : xw2;
    const float* dw = (dir == 0) ? dw0 : (dir == 1) ? dw1 : dw2;
    const float* db = (dir == 0) ? db0 : (dir == 1) ? db1 : db2;
    const float* cw = (dir == 0) ? cw0 : (dir == 1) ? cw1 : cw2;
    const float* cb = (dir == 0) ? cb0 : (dir == 1) ? cb1 : cb2;
    const float* xzb = ws + XZ_OFF + (size_t)b * 4096 * 512;
    float* ub      = ws + U_OFF + (size_t)dir * DIR_SZ + (size_t)b * 256 * 4096;
    float* deltab  = ws + DELTA_OFF + (size_t)dir * DIR_SZ + (size_t)b * 256 * 4096;
    float* Bf      = ws + BC_OFF + (size_t)dir * BC_SZ;
    float* Cf      = Bf + BC_SZ / 2;

    __shared__ float xt[35 * 260];   // staging [k][d], k = scan-window row, stride 260 (16B mult)
    __shared__ float xd[40 * 33];
    float* ut = xt;                  // reused after conv: [li][264] swizzled (8448 <= 9100)

    // ---- stage 35 rows, each a coalesced 1KB read of xz[row][0..255]
    for (int idx = threadIdx.x; idx < 35 * 64; idx += 256) {
        int k = idx >> 6, dq = idx & 63;
        int j = l0 - 3 + k;
        float4 v = {0.f, 0.f, 0.f, 0.f};
        if (j >= 0) {
            int row = (dir == 0) ? j : (dir == 1) ? (4095 - j) : (((j & 15) << 8) | (j >> 4));
            v = *(const float4*)(xzb + (size_t)row * 512 + dq * 4);
        }
        *(float4*)(xt + k * 260 + dq * 4) = v;
    }
    __syncthreads();

    // ---- conv + silu, thread = d row (reads column d of xt, conflict-free)
    const int d = threadIdx.x;
    const float w0 = cw[d * 4 + 0], w1 = cw[d * 4 + 1], w2 = cw[d * 4 + 2], w3 = cw[d * 4 + 3];
    const float bb = cb[d];
    float win[35];
    #pragma unroll
    for (int k = 0; k < 35; ++k) win[k] = xt[k * 260 + d];
    float r[32];
    #pragma unroll
    for (int li = 0; li < 32; ++li)
        r[li] = siluf_(bb + w0 * win[li] + w1 * win[li + 1] + w2 * win[li + 2] + w3 * win[li + 3]);
    // write u (scan input, scan-domain rows)
    {
        float* urow = ub + (size_t)d * 4096 + l0;
        #pragma unroll
        for (int q = 0; q < 8; ++q) {
            float4 v; v.x = r[q*4]; v.y = r[q*4+1]; v.z = r[q*4+2]; v.w = r[q*4+3];
            *(float4*)(urow + q * 4) = v;
        }
    }
    __syncthreads();   // all xt reads done before ut overwrite

    // store u-tile swizzled: ut[li][ 4*((d>>2)^(li&7)) + (d&3) ]
    #pragma unroll
    for (int li = 0; li < 32; ++li)
        ut[li * 264 + 4 * (((d >> 2) ^ (li & 7))) + (d & 3)] = r[li];
    __syncthreads();

    // ---- 40x256 GEMM: xd[40][32] = xw @ u-tile
    {
        const int rg = threadIdx.x >> 5;
        const int li = threadIdx.x & 31;
        float acc[5];
        #pragma unroll
        for (int j = 0; j < 5; ++j) acc[j] = 0.0f;
        const float* up = ut + li * 264;
        const int sw = (li & 7);
        #pragma unroll 2
        for (int c4 = 0; c4 < 64; ++c4) {
            float4 uv = *(const float4*)(up + 4 * (c4 ^ sw));
            const int c = 4 * (c4 ^ sw);
            #pragma unroll
            for (int j = 0; j < 5; ++j) {
                float4 wv = *(const float4*)(xw + (size_t)(rg * 5 + j) * 256 + c);
                acc[j] += wv.x * uv.x + wv.y * uv.y + wv.z * uv.z + wv.w * uv.w;
            }
        }
        #pragma unroll
        for (int j = 0; j < 5; ++j) xd[(rg * 5 + j) * 33 + li] = acc[j];
    }
    __syncthreads();

    // ---- B/C blocked writes (wave-coalesced) + delta
    {
        const int wv = threadIdx.x >> 6;
        const int lane = threadIdx.x & 63;
        const int n = lane >> 2, lq = lane & 3;
        #pragma unroll
        for (int j = 0; j < 2; ++j) {
            int l4 = (l0 >> 2) + j * 4 + wv;
            int li = (j * 4 + wv) * 4 + lq;
            size_t base = (((size_t)b * 1024 + l4) * 16 + n) * 4 + lq;
            Bf[base] = xd[(8 + n) * 33 + li];
            Cf[base] = xd[(24 + n) * 33 + li];
        }
    }
    {
        const int li = threadIdx.x & 31;
        float xr8[8];
        #pragma unroll
        for (int rr = 0; rr < 8; ++rr) xr8[rr] = xd[rr * 33 + li];
        #pragma unroll
        for (int k = 0; k < 32; ++k) {
            int dd = ((threadIdx.x + k * 256) >> 5);
            float4 wa = *(const float4*)(dw + dd * 8);
            float4 wb = *(const float4*)(dw + dd * 8 + 4);
            float acc = db[dd]
                + wa.x * xr8[0] + wa.y * xr8[1] + wa.z * xr8[2] + wa.w * xr8[3]
                + wb.x * xr8[4] + wb.y * xr8[5] + wb.z * xr8[6] + wb.w * xr8[7];
            deltab[(size_t)dd * 4096 + l0 + li] = softplusf_(acc);
        }
    }
}

// ---------------------------------------------------------------------------
// K3: chunked selective scan. Block = (b,d,dir) row: 512 thr = 32 chunks x 16 states.
__global__ __launch_bounds__(512) void scan_kernel(float* __restrict__ ws,
                            const float* __restrict__ Al0, const float* __restrict__ Dp0,
                            const float* __restrict__ Al1, const float* __restrict__ Dp1,
                            const float* __restrict__ Al2, const float* __restrict__ Dp2) {
    const int d = blockIdx.x, b = blockIdx.y, dir = blockIdx.z;
    const float* Al = (dir == 0) ? Al0 : (dir == 1) ? Al1 : Al2;
    const float* Dp = (dir == 0) ? Dp0 : (dir == 1) ? Dp1 : Dp2;
    const int c = threadIdx.x >> 4;     // chunk 0..31
    const int n = threadIdx.x & 15;     // state 0..15
    const int qid = n >> 2;             // quad within chunk
    const float Ane = -1.44269504f * __expf(Al[d * 16 + n]);   // exp(An*x) = 2^(Ane*x)
    const float Dd = Dp[d];
    const float* urow = ws + U_OFF + (size_t)dir * DIR_SZ + ((size_t)(b * 256 + d)) * 4096;
    float* drow = ws + DELTA_OFF + (size_t)dir * DIR_SZ + ((size_t)(b * 256 + d)) * 4096;

    __shared__ float sdu[32 * 260];     // [chunk][(dv,du) x128 + pad]
    __shared__ float red[32 * 34];      // union: {Psh[512],Ssh[512]} then mat[32][34]
    float* Psh = red;
    float* Ssh = red + 512;

    {
        const float4* d4 = (const float4*)drow;
        const float4* u4 = (const float4*)urow;
        for (int i = threadIdx.x; i < 1024; i += 512) {
            float4 dv = d4[i], uv = u4[i];
            int l = i * 4;
            float* p = sdu + (l >> 7) * 260 + (l & 127) * 2;
            float4 a, bq;
            a.x = dv.x; a.y = dv.x * uv.x; a.z = dv.y; a.w = dv.y * uv.y;
            bq.x = dv.z; bq.y = dv.z * uv.z; bq.z = dv.w; bq.w = dv.w * uv.w;
            *(float4*)(p) = a; *(float4*)(p + 4) = bq;
        }
    }
    __syncthreads();

    const float4* Bq = (const float4*)(ws + BC_OFF + (size_t)dir * BC_SZ)
                       + ((size_t)b * 1024 + c * 32) * 16 + n;
    const float4* Cq = (const float4*)(ws + BC_OFF + (size_t)dir * BC_SZ + BC_SZ / 2)
                       + ((size_t)b * 1024 + c * 32) * 16 + n;
    const float4* sp = (const float4*)(sdu + c * 260);

    // Pass 1: local scan + decay-sum (exps are h-independent: batch per float4)
    float S = 0.0f, dsum = 0.0f;
    #pragma unroll 8
    for (int k4 = 0; k4 < 32; ++k4) {
        float4 a = sp[k4 * 2], bq = sp[k4 * 2 + 1];
        float4 Bv = Bq[(size_t)k4 * 16];
        float e0 = EXP2(Ane * a.x), e1 = EXP2(Ane * a.z);
        float e2 = EXP2(Ane * bq.x), e3 = EXP2(Ane * bq.z);
        dsum += (a.x + a.z) + (bq.x + bq.z);
        S = S * e0 + a.y * Bv.x;
        S = S * e1 + a.w * Bv.y;
        S = S * e2 + bq.y * Bv.z;
        S = S * e3 + bq.w * Bv.w;
    }
    Ssh[c * 16 + n] = S;
    Psh[c * 16 + n] = EXP2(Ane * dsum);
    __syncthreads();
    float h = 0.0f;
    for (int k = 0; k < c; ++k) h = h * Psh[k * 16 + n] + Ssh[k * 16 + n];
    __syncthreads();   // Psh/Ssh fully consumed; red region becomes mat

    // Pass 2: rescan; per step 2 DPP quad stages + 1 LDS write; harvest each 8 steps.
    #define SCAN_STEP(t, ee, du, Bn, Cn) { \
        h = h * (ee) + (du) * (Bn); \
        float yp = h * (Cn); \
        yp += DPP_MOV(yp, 0xB1); \
        yp += DPP_MOV(yp, 0x4E); \
        red[(4 * (t) + qid) * 34 + c] = yp; }

    for (int g = 0; g < 16; ++g) {
        float4 a0 = sp[g * 4 + 0], a1 = sp[g * 4 + 1];
        float4 a2 = sp[g * 4 + 2], a3 = sp[g * 4 + 3];
        float4 Bv0 = Bq[(size_t)(g * 2) * 16], Bv1 = Bq[(size_t)(g * 2 + 1) * 16];
        float4 Cv0 = Cq[(size_t)(g * 2) * 16], Cv1 = Cq[(size_t)(g * 2 + 1) * 16];
        float e0 = EXP2(Ane * a0.x), e1 = EXP2(Ane * a0.z);
        float e2 = EXP2(Ane * a1.x), e3 = EXP2(Ane * a1.z);
        float e4 = EXP2(Ane * a2.x), e5 = EXP2(Ane * a2.z);
        float e6 = EXP2(Ane * a3.x), e7 = EXP2(Ane * a3.z);
        SCAN_STEP(0, e0, a0.y, Bv0.x, Cv0.x)
        SCAN_STEP(1, e1, a0.w, Bv0.y, Cv0.y)
        SCAN_STEP(2, e2, a1.y, Bv0.z, Cv0.z)
        SCAN_STEP(3, e3, a1.w, Bv0.w, Cv0.w)
        SCAN_STEP(4, e4, a2.y, Bv1.x, Cv1.x)
        SCAN_STEP(5, e5, a2.w, Bv1.y, Cv1.y)
        SCAN_STEP(6, e6, a3.y, Bv1.z, Cv1.z)
        SCAN_STEP(7, e7, a3.w, Bv1.w, Cv1.w)
        const int tt = n & 7;
        float q0 = red[(4 * tt + 0) * 34 + c];
        float q1 = red[(4 * tt + 1) * 34 + c];
        float q2 = red[(4 * tt + 2) * 34 + c];
        float q3 = red[(4 * tt + 3) * 34 + c];
        float y = (q0 + q1) + (q2 + q3);
        if (n < 8) {
            int gl = c * 128 + g * 8 + n;
            drow[perm_idx(dir, gl)] = y + Dd * urow[gl];
        }
    }
    #undef SCAN_STEP
}

// ---------------------------------------------------------------------------
// K4: y_total = silu(z)*(yf+yb+ys); out = out_proj_w @ y_total.
// 16-l tiles (grid 1024, ~4 blocks/CU). ow read directly (one o-row per thread,
// sequential walk -> L1-resident; no transpose kernel needed).
__global__ __launch_bounds__(256) void epilogue_kernel(const float* __restrict__ ws,
                                const float* __restrict__ ow,
                                float* __restrict__ out) {
    const int l0 = blockIdx.x * 16, b = blockIdx.y;
    __shared__ float yt[256 * 20];
    const float* yf = ws + DELTA_OFF;
    const float* yb = ws + DELTA_OFF + DIR_SZ;
    const float* ysd = ws + DELTA_OFF + 2 * DIR_SZ;
    const float* xzb = ws + XZ_OFF + (size_t)b * 4096 * 512;

    // phase 1: y-sum, vectorized f4 (coalesced)
    for (int idx = threadIdx.x; idx < 256 * 4; idx += 256) {
        int d = idx >> 2, q = (idx & 3) * 4;
        size_t ro = ((size_t)(b * 256 + d)) * 4096 + l0 + q;
        float4 vf = *(const float4*)(yf + ro);
        float4 vb = *(const float4*)(yb + ro);
        float4 vs = *(const float4*)(ysd + ro);
        float4 s; s.x = vf.x + vb.x + vs.x; s.y = vf.y + vb.y + vs.y;
        s.z = vf.z + vb.z + vs.z; s.w = vf.w + vb.w + vs.w;
        *(float4*)(yt + d * 20 + q) = s;
    }
    __syncthreads();
    // phase 2: multiply silu(z), z read coalesced from xz[b][l][256+d]
    {
        const int d = threadIdx.x;
        #pragma unroll 4
        for (int li = 0; li < 16; ++li) {
            float z = xzb[(size_t)(l0 + li) * 512 + 256 + d];
            yt[d * 20 + li] *= siluf_(z);
        }
    }
    __syncthreads();

    // GEMM: thread = (o, l-group of 8)
    const int o   = threadIdx.x & 127;
    const int li0 = (threadIdx.x >> 7) * 8;
    float acc[8];
    #pragma unroll
    for (int k = 0; k < 8; ++k) acc[k] = 0.0f;
    const float* wrow = ow + (size_t)o * 256;
    for (int d = 0; d < 256; ++d) {
        float w = wrow[d];
        float4 y0 = *(const float4*)(yt + d * 20 + li0);
        float4 y1 = *(const float4*)(yt + d * 20 + li0 + 4);
        acc[0] += w * y0.x; acc[1] += w * y0.y; acc[2] += w * y0.z; acc[3] += w * y0.w;
        acc[4] += w * y1.x; acc[5] += w * y1.y; acc[6] += w * y1.z; acc[7] += w * y1.w;
    }
    #pragma unroll
    for (int k = 0; k < 8; ++k)
        out[((size_t)(b * 4096 + l0 + li0 + k)) * 128 + o] = acc[k];
}

// ---------------------------------------------------------------------------
extern "C" void kernel_launch(void* const* d_in, const int* in_sizes, int n_in,
                              void* d_out, int out_size, void* d_ws, size_t ws_size,
                              hipStream_t stream) {
    const float* x_in = (const float*)d_in[0];
    const float* ipw  = (const float*)d_in[1];
    const float* cw[3]  = {(const float*)d_in[2],  (const float*)d_in[9],  (const float*)d_in[16]};
    const float* cb[3]  = {(const float*)d_in[3],  (const float*)d_in[10], (const float*)d_in[17]};
    const float* xpw[3] = {(const float*)d_in[4],  (const float*)d_in[11], (const float*)d_in[18]};
    const float* dtw[3] = {(const float*)d_in[5],  (const float*)d_in[12], (const float*)d_in[19]};
    const float* dtb[3] = {(const float*)d_in[6],  (const float*)d_in[13], (const float*)d_in[20]};
    const float* alog[3]= {(const float*)d_in[7],  (const float*)d_in[14], (const float*)d_in[21]};
    const float* dp[3]  = {(const float*)d_in[8],  (const float*)d_in[15], (const float*)d_in[22]};
    const float* ow   = (const float*)d_in[23];
    float* ws  = (float*)d_ws;
    float* out = (float*)d_out;

    transpose_in_kernel<<<dim3(256), 256, 0, stream>>>(ipw, ws + WTIN_OFF);
    inproj_kernel<<<dim3(256, 4), 256, 0, stream>>>(x_in, ws + WTIN_OFF, ws);
    front_kernel<<<dim3(128, 4, 3), 256, 0, stream>>>(ws,
        xpw[0], xpw[1], xpw[2], dtw[0], dtw[1], dtw[2], dtb[0], dtb[1], dtb[2],
        cw[0], cb[0], cw[1], cb[1], cw[2], cb[2]);
    scan_kernel<<<dim3(256, 4, 3), 512, 0, stream>>>(ws,
        alog[0], dp[0], alog[1], dp[1], alog[2], dp[2]);
    epilogue_kernel<<<dim3(256, 4), 256, 0, stream>>>(ws, ow, out);
}

// Round 8
// 401.844 us; speedup vs baseline: 7.0526x; 1.0621x over previous
//
#include <hip/hip_runtime.h>
#include <math.h>

// Problem constants
// B=4, H=W=64 -> L=4096, DIM=128, D_INNER=256, D_STATE=16, D_CONV=4, DT_RANK=8, NSLICES=16
#define LSEQ 4096

// Workspace layout (floats). Total ~140 MB (proven to fit)
// xz stored [b][l][p] (p-contiguous rows of 512): conv windows for ALL dirs are
// coalesced row gathers.
#define XZ_OFF   0ULL
#define XZ_SZ    (4ULL * 4096 * 512)
#define U_OFF    (XZ_OFF + XZ_SZ)
#define DIR_SZ   (4ULL * 256 * 4096)        // per direction
#define DELTA_OFF (U_OFF + 3ULL * DIR_SZ)   // delta; also holds wT_in before front runs
#define BC_OFF   (DELTA_OFF + 3ULL * DIR_SZ)
#define BC_SZ    (4ULL * 4096 * 32)         // per dir: B blocked [b][1024][16][4] then C blocked
#define WTIN_OFF DELTA_OFF                  // wT_in[128][512]; delta written later by front
#define WTOUT_OFF U_OFF                     // wT_out[256][128]; u dead after scan

__device__ __forceinline__ float sigmoidf_(float x) { return 1.0f / (1.0f + __expf(-x)); }
__device__ __forceinline__ float siluf_(float x)    { return x * sigmoidf_(x); }

// 2^x via HW transcendental.
__device__ __forceinline__ float fast_exp2_asm(float x) {
    float r;
    asm volatile("v_exp_f32 %0, %1\n\ts_nop 0" : "=v"(r) : "v"(x));
    return r;
}
#if defined(__has_builtin)
#if __has_builtin(__builtin_amdgcn_exp2f)
#define EXP2(x) __builtin_amdgcn_exp2f(x)
#else
#define EXP2(x) fast_exp2_asm(x)
#endif
#else
#define EXP2(x) fast_exp2_asm(x)
#endif

// softplus via HW exp2/log2: ln(1+e^x) = ln2 * log2(1 + 2^(x*log2e))
__device__ __forceinline__ float softplus_fast(float x) {
    float t = EXP2(1.44269504f * x);
    float r = 0.69314718f * __log2f(1.0f + t);
    return (x > 20.0f) ? x : r;
}

// dir permutation: scan-domain index j -> original-domain index
__device__ __forceinline__ int perm_idx(int dir, int j) {
    if (dir == 0) return j;
    if (dir == 1) return 4095 - j;
    return ((j & 15) << 8) | (j >> 4);   // slice: j = jj*16+s -> s*256+jj
}

// DPP cross-lane move (VALU pipe, no LDS). ctrl must be a literal.
#define DPP_MOV(x, ctrl) __int_as_float(__builtin_amdgcn_update_dpp(0, __float_as_int(x), (ctrl), 0xF, 0xF, true))

// ---------------------------------------------------------------------------
// K0: wT_in[c][p] = in_proj_w[p][c]   (128 x 512)
__global__ __launch_bounds__(256) void transpose_in_kernel(const float* __restrict__ w,
                                                           float* __restrict__ wT) {
    int idx = blockIdx.x * 256 + threadIdx.x;   // 65536
    int p = idx >> 7, c = idx & 127;
    wT[(size_t)c * 512 + p] = w[(size_t)p * 128 + c];
}

// ---------------------------------------------------------------------------
// K1: xz[b][l][p] = sum_c wT_in[c][p] * x_in[b][l][c]
__global__ __launch_bounds__(256) void inproj_kernel(const float* __restrict__ x,
                              const float* __restrict__ wT,
                              float* __restrict__ xz) {
    const int b = blockIdx.y;
    const int l0 = blockIdx.x * 16;
    __shared__ float xs[128 * 20];   // [c][l]
    for (int idx = threadIdx.x; idx < 16 * 128; idx += 256) {
        int li = idx >> 7, c = idx & 127;
        xs[c * 20 + li] = x[((size_t)(b * 4096 + l0 + li)) * 128 + c];
    }
    __syncthreads();
    const int p0 = (threadIdx.x & 127) * 4;
    const int g8 = (threadIdx.x >> 7) * 8;
    float acc[4][8];
    #pragma unroll
    for (int j = 0; j < 4; ++j)
        #pragma unroll
        for (int k = 0; k < 8; ++k) acc[j][k] = 0.0f;
    for (int c = 0; c < 128; ++c) {
        float4 wv = *(const float4*)(wT + (size_t)c * 512 + p0);
        const float* xp = xs + c * 20 + g8;
        float4 x0 = *(const float4*)(xp);
        float4 x1 = *(const float4*)(xp + 4);
        float xv[8] = {x0.x, x0.y, x0.z, x0.w, x1.x, x1.y, x1.z, x1.w};
        float wj[4] = {wv.x, wv.y, wv.z, wv.w};
        #pragma unroll
        for (int j = 0; j < 4; ++j)
            #pragma unroll
            for (int k = 0; k < 8; ++k) acc[j][k] += wj[j] * xv[k];
    }
    #pragma unroll
    for (int k = 0; k < 8; ++k) {
        float4 s; s.x = acc[0][k]; s.y = acc[1][k]; s.z = acc[2][k]; s.w = acc[3][k];
        *(float4*)(xz + ((size_t)(b * 4096 + l0 + g8 + k)) * 512 + p0) = s;
    }
}

// ---------------------------------------------------------------------------
// K2 (fused conv+silu+x_proj+dt, ALL dirs): per (32-scan-l tile, b, dir).
__global__ __launch_bounds__(256) void front_kernel(float* __restrict__ ws,
        const float* __restrict__ xw0, const float* __restrict__ xw1, const float* __restrict__ xw2,
        const float* __restrict__ dw0, const float* __restrict__ dw1, const float* __restrict__ dw2,
        const float* __restrict__ db0, const float* __restrict__ db1, const float* __restrict__ db2,
        const float* __restrict__ cw0, const float* __restrict__ cb0,
        const float* __restrict__ cw1, const float* __restrict__ cb1,
        const float* __restrict__ cw2, const float* __restrict__ cb2) {
    const int l0 = blockIdx.x * 32, b = blockIdx.y, dir = blockIdx.z;
    const float* xw = (dir == 0) ? xw0 : (dir == 1) ? xw1 : xw2;
    const float* dw = (dir == 0) ? dw0 : (dir == 1) ? dw1 : dw2;
    const float* db = (dir == 0) ? db0 : (dir == 1) ? db1 : db2;
    const float* cw = (dir == 0) ? cw0 : (dir == 1) ? cw1 : cw2;
    const float* cb = (dir == 0) ? cb0 : (dir == 1) ? cb1 : cb2;
    const float* xzb = ws + XZ_OFF + (size_t)b * 4096 * 512;
    float* ub      = ws + U_OFF + (size_t)dir * DIR_SZ + (size_t)b * 256 * 4096;
    float* deltab  = ws + DELTA_OFF + (size_t)dir * DIR_SZ + (size_t)b * 256 * 4096;
    float* Bf      = ws + BC_OFF + (size_t)dir * BC_SZ;
    float* Cf      = Bf + BC_SZ / 2;

    __shared__ float xt[35 * 260];   // staging [k][d]
    __shared__ float xd[40 * 33];
    float* ut = xt;                  // reused after conv: [li][264] swizzled

    // ---- stage 35 rows, each a coalesced 1KB read of xz[row][0..255]
    for (int idx = threadIdx.x; idx < 35 * 64; idx += 256) {
        int k = idx >> 6, dq = idx & 63;
        int j = l0 - 3 + k;
        float4 v = {0.f, 0.f, 0.f, 0.f};
        if (j >= 0) {
            int row = (dir == 0) ? j : (dir == 1) ? (4095 - j) : (((j & 15) << 8) | (j >> 4));
            v = *(const float4*)(xzb + (size_t)row * 512 + dq * 4);
        }
        *(float4*)(xt + k * 260 + dq * 4) = v;
    }
    __syncthreads();

    // ---- conv + silu, thread = d row
    const int d = threadIdx.x;
    const float w0 = cw[d * 4 + 0], w1 = cw[d * 4 + 1], w2 = cw[d * 4 + 2], w3 = cw[d * 4 + 3];
    const float bb = cb[d];
    float win[35];
    #pragma unroll
    for (int k = 0; k < 35; ++k) win[k] = xt[k * 260 + d];
    float r[32];
    #pragma unroll
    for (int li = 0; li < 32; ++li)
        r[li] = siluf_(bb + w0 * win[li] + w1 * win[li + 1] + w2 * win[li + 2] + w3 * win[li + 3]);
    {
        float* urow = ub + (size_t)d * 4096 + l0;
        #pragma unroll
        for (int q = 0; q < 8; ++q) {
            float4 v; v.x = r[q*4]; v.y = r[q*4+1]; v.z = r[q*4+2]; v.w = r[q*4+3];
            *(float4*)(urow + q * 4) = v;
        }
    }
    __syncthreads();   // all xt reads done before ut overwrite

    #pragma unroll
    for (int li = 0; li < 32; ++li)
        ut[li * 264 + 4 * (((d >> 2) ^ (li & 7))) + (d & 3)] = r[li];
    __syncthreads();

    // ---- 40x256 GEMM: xd[40][32] = xw @ u-tile
    {
        const int rg = threadIdx.x >> 5;
        const int li = threadIdx.x & 31;
        float acc[5];
        #pragma unroll
        for (int j = 0; j < 5; ++j) acc[j] = 0.0f;
        const float* up = ut + li * 264;
        const int sw = (li & 7);
        #pragma unroll 2
        for (int c4 = 0; c4 < 64; ++c4) {
            float4 uv = *(const float4*)(up + 4 * (c4 ^ sw));
            const int c = 4 * (c4 ^ sw);
            #pragma unroll
            for (int j = 0; j < 5; ++j) {
                float4 wv = *(const float4*)(xw + (size_t)(rg * 5 + j) * 256 + c);
                acc[j] += wv.x * uv.x + wv.y * uv.y + wv.z * uv.z + wv.w * uv.w;
            }
        }
        #pragma unroll
        for (int j = 0; j < 5; ++j) xd[(rg * 5 + j) * 33 + li] = acc[j];
    }
    __syncthreads();

    // ---- B/C blocked writes (wave-coalesced) + delta
    {
        const int wv = threadIdx.x >> 6;
        const int lane = threadIdx.x & 63;
        const int n = lane >> 2, lq = lane & 3;
        #pragma unroll
        for (int j = 0; j < 2; ++j) {
            int l4 = (l0 >> 2) + j * 4 + wv;
            int li = (j * 4 + wv) * 4 + lq;
            size_t base = (((size_t)b * 1024 + l4) * 16 + n) * 4 + lq;
            Bf[base] = xd[(8 + n) * 33 + li];
            Cf[base] = xd[(24 + n) * 33 + li];
        }
    }
    {
        const int li = threadIdx.x & 31;
        float xr8[8];
        #pragma unroll
        for (int rr = 0; rr < 8; ++rr) xr8[rr] = xd[rr * 33 + li];
        #pragma unroll
        for (int k = 0; k < 32; ++k) {
            int dd = ((threadIdx.x + k * 256) >> 5);
            float4 wa = *(const float4*)(dw + dd * 8);
            float4 wb = *(const float4*)(dw + dd * 8 + 4);
            float acc = db[dd]
                + wa.x * xr8[0] + wa.y * xr8[1] + wa.z * xr8[2] + wa.w * xr8[3]
                + wb.x * xr8[4] + wb.y * xr8[5] + wb.z * xr8[6] + wb.w * xr8[7];
            deltab[(size_t)dd * 4096 + l0 + li] = softplus_fast(acc);
        }
    }
}

// ---------------------------------------------------------------------------
// K3: chunked selective scan. Block = (b,d,dir) row: 512 thr = 32 chunks x 16 states.
__global__ __launch_bounds__(512) void scan_kernel(float* __restrict__ ws,
                            const float* __restrict__ Al0, const float* __restrict__ Dp0,
                            const float* __restrict__ Al1, const float* __restrict__ Dp1,
                            const float* __restrict__ Al2, const float* __restrict__ Dp2) {
    const int d = blockIdx.x, b = blockIdx.y, dir = blockIdx.z;
    const float* Al = (dir == 0) ? Al0 : (dir == 1) ? Al1 : Al2;
    const float* Dp = (dir == 0) ? Dp0 : (dir == 1) ? Dp1 : Dp2;
    const int c = threadIdx.x >> 4;     // chunk 0..31
    const int n = threadIdx.x & 15;     // state 0..15
    const int qid = n >> 2;             // quad within chunk
    const float Ane = -1.44269504f * __expf(Al[d * 16 + n]);
    const float Dd = Dp[d];
    const float* urow = ws + U_OFF + (size_t)dir * DIR_SZ + ((size_t)(b * 256 + d)) * 4096;
    float* drow = ws + DELTA_OFF + (size_t)dir * DIR_SZ + ((size_t)(b * 256 + d)) * 4096;

    __shared__ float sdu[32 * 260];
    __shared__ float red[32 * 34];
    float* Psh = red;
    float* Ssh = red + 512;

    {
        const float4* d4 = (const float4*)drow;
        const float4* u4 = (const float4*)urow;
        for (int i = threadIdx.x; i < 1024; i += 512) {
            float4 dv = d4[i], uv = u4[i];
            int l = i * 4;
            float* p = sdu + (l >> 7) * 260 + (l & 127) * 2;
            float4 a, bq;
            a.x = dv.x; a.y = dv.x * uv.x; a.z = dv.y; a.w = dv.y * uv.y;
            bq.x = dv.z; bq.y = dv.z * uv.z; bq.z = dv.w; bq.w = dv.w * uv.w;
            *(float4*)(p) = a; *(float4*)(p + 4) = bq;
        }
    }
    __syncthreads();

    const float4* Bq = (const float4*)(ws + BC_OFF + (size_t)dir * BC_SZ)
                       + ((size_t)b * 1024 + c * 32) * 16 + n;
    const float4* Cq = (const float4*)(ws + BC_OFF + (size_t)dir * BC_SZ + BC_SZ / 2)
                       + ((size_t)b * 1024 + c * 32) * 16 + n;
    const float4* sp = (const float4*)(sdu + c * 260);

    // Pass 1: local scan + decay-sum
    float S = 0.0f, dsum = 0.0f;
    #pragma unroll 8
    for (int k4 = 0; k4 < 32; ++k4) {
        float4 a = sp[k4 * 2], bq = sp[k4 * 2 + 1];
        float4 Bv = Bq[(size_t)k4 * 16];
        float e0 = EXP2(Ane * a.x), e1 = EXP2(Ane * a.z);
        float e2 = EXP2(Ane * bq.x), e3 = EXP2(Ane * bq.z);
        dsum += (a.x + a.z) + (bq.x + bq.z);
        S = S * e0 + a.y * Bv.x;
        S = S * e1 + a.w * Bv.y;
        S = S * e2 + bq.y * Bv.z;
        S = S * e3 + bq.w * Bv.w;
    }
    Ssh[c * 16 + n] = S;
    Psh[c * 16 + n] = EXP2(Ane * dsum);
    __syncthreads();
    float h = 0.0f;
    for (int k = 0; k < c; ++k) h = h * Psh[k * 16 + n] + Ssh[k * 16 + n];
    __syncthreads();   // Psh/Ssh consumed; red becomes mat

    #define SCAN_STEP(t, ee, du, Bn, Cn) { \
        h = h * (ee) + (du) * (Bn); \
        float yp = h * (Cn); \
        yp += DPP_MOV(yp, 0xB1); \
        yp += DPP_MOV(yp, 0x4E); \
        red[(4 * (t) + qid) * 34 + c] = yp; }

    for (int g = 0; g < 16; ++g) {
        float4 a0 = sp[g * 4 + 0], a1 = sp[g * 4 + 1];
        float4 a2 = sp[g * 4 + 2], a3 = sp[g * 4 + 3];
        float4 Bv0 = Bq[(size_t)(g * 2) * 16], Bv1 = Bq[(size_t)(g * 2 + 1) * 16];
        float4 Cv0 = Cq[(size_t)(g * 2) * 16], Cv1 = Cq[(size_t)(g * 2 + 1) * 16];
        float e0 = EXP2(Ane * a0.x), e1 = EXP2(Ane * a0.z);
        float e2 = EXP2(Ane * a1.x), e3 = EXP2(Ane * a1.z);
        float e4 = EXP2(Ane * a2.x), e5 = EXP2(Ane * a2.z);
        float e6 = EXP2(Ane * a3.x), e7 = EXP2(Ane * a3.z);
        SCAN_STEP(0, e0, a0.y, Bv0.x, Cv0.x)
        SCAN_STEP(1, e1, a0.w, Bv0.y, Cv0.y)
        SCAN_STEP(2, e2, a1.y, Bv0.z, Cv0.z)
        SCAN_STEP(3, e3, a1.w, Bv0.w, Cv0.w)
        SCAN_STEP(4, e4, a2.y, Bv1.x, Cv1.x)
        SCAN_STEP(5, e5, a2.w, Bv1.y, Cv1.y)
        SCAN_STEP(6, e6, a3.y, Bv1.z, Cv1.z)
        SCAN_STEP(7, e7, a3.w, Bv1.w, Cv1.w)
        const int tt = n & 7;
        float q0 = red[(4 * tt + 0) * 34 + c];
        float q1 = red[(4 * tt + 1) * 34 + c];
        float q2 = red[(4 * tt + 2) * 34 + c];
        float q3 = red[(4 * tt + 3) * 34 + c];
        float y = (q0 + q1) + (q2 + q3);
        if (n < 8) {
            int gl = c * 128 + g * 8 + n;
            drow[perm_idx(dir, gl)] = y + Dd * urow[gl];
        }
    }
    #undef SCAN_STEP
}

// ---------------------------------------------------------------------------
// K3b: wT_out[d][o] = out_proj_w[o][d]  (runs AFTER scan; lives in dead U region)
__global__ __launch_bounds__(256) void transpose_w_kernel(const float* __restrict__ ow,
                                                          float* __restrict__ wT) {
    int idx = blockIdx.x * 256 + threadIdx.x;   // 32768
    int o = idx >> 8, d = idx & 255;            // read side coalesced (d consecutive)
    wT[(size_t)d * 128 + o] = ow[(size_t)o * 256 + d];
}

// ---------------------------------------------------------------------------
// K4: y_total = silu(z)*(yf+yb+ys); out = wT^T @ y_total.
// GEMM reads wT[d][o] lane-coalesced float4 (512B/inst) — fixes r7's 64-line gather.
__global__ __launch_bounds__(256) void epilogue_kernel(const float* __restrict__ ws,
                                const float* __restrict__ wT,
                                float* __restrict__ out) {
    const int l0 = blockIdx.x * 16, b = blockIdx.y;
    __shared__ float yt[256 * 20];
    const float* yf = ws + DELTA_OFF;
    const float* yb = ws + DELTA_OFF + DIR_SZ;
    const float* ysd = ws + DELTA_OFF + 2 * DIR_SZ;
    const float* xzb = ws + XZ_OFF + (size_t)b * 4096 * 512;

    // phase 1: y-sum, vectorized f4 (coalesced)
    for (int idx = threadIdx.x; idx < 256 * 4; idx += 256) {
        int d = idx >> 2, q = (idx & 3) * 4;
        size_t ro = ((size_t)(b * 256 + d)) * 4096 + l0 + q;
        float4 vf = *(const float4*)(yf + ro);
        float4 vb = *(const float4*)(yb + ro);
        float4 vs = *(const float4*)(ysd + ro);
        float4 s; s.x = vf.x + vb.x + vs.x; s.y = vf.y + vb.y + vs.y;
        s.z = vf.z + vb.z + vs.z; s.w = vf.w + vb.w + vs.w;
        *(float4*)(yt + d * 20 + q) = s;
    }
    __syncthreads();
    // phase 2: multiply silu(z), z read coalesced from xz[b][l][256+d]
    {
        const int d = threadIdx.x;
        #pragma unroll 4
        for (int li = 0; li < 16; ++li) {
            float z = xzb[(size_t)(l0 + li) * 512 + 256 + d];
            yt[d * 20 + li] *= siluf_(z);
        }
    }
    __syncthreads();

    // GEMM: thread = (4 o, 2 l)
    const int o0 = (threadIdx.x & 31) * 4;
    const int lp = (threadIdx.x >> 5) * 2;
    float a0[4], a1[4];
    #pragma unroll
    for (int j = 0; j < 4; ++j) { a0[j] = 0.0f; a1[j] = 0.0f; }
    #pragma unroll 4
    for (int d = 0; d < 256; ++d) {
        float4 w = *(const float4*)(wT + (size_t)d * 128 + o0);
        float2 y = *(const float2*)(yt + d * 20 + lp);
        a0[0] += w.x * y.x; a0[1] += w.y * y.x; a0[2] += w.z * y.x; a0[3] += w.w * y.x;
        a1[0] += w.x * y.y; a1[1] += w.y * y.y; a1[2] += w.z * y.y; a1[3] += w.w * y.y;
    }
    float4 s0; s0.x = a0[0]; s0.y = a0[1]; s0.z = a0[2]; s0.w = a0[3];
    float4 s1; s1.x = a1[0]; s1.y = a1[1]; s1.z = a1[2]; s1.w = a1[3];
    *(float4*)(out + ((size_t)(b * 4096 + l0 + lp)) * 128 + o0) = s0;
    *(float4*)(out + ((size_t)(b * 4096 + l0 + lp + 1)) * 128 + o0) = s1;
}

// ---------------------------------------------------------------------------
extern "C" void kernel_launch(void* const* d_in, const int* in_sizes, int n_in,
                              void* d_out, int out_size, void* d_ws, size_t ws_size,
                              hipStream_t stream) {
    const float* x_in = (const float*)d_in[0];
    const float* ipw  = (const float*)d_in[1];
    const float* cw[3]  = {(const float*)d_in[2],  (const float*)d_in[9],  (const float*)d_in[16]};
    const float* cb[3]  = {(const float*)d_in[3],  (const float*)d_in[10], (const float*)d_in[17]};
    const float* xpw[3] = {(const float*)d_in[4],  (const float*)d_in[11], (const float*)d_in[18]};
    const float* dtw[3] = {(const float*)d_in[5],  (const float*)d_in[12], (const float*)d_in[19]};
    const float* dtb[3] = {(const float*)d_in[6],  (const float*)d_in[13], (const float*)d_in[20]};
    const float* alog[3]= {(const float*)d_in[7],  (const float*)d_in[14], (const float*)d_in[21]};
    const float* dp[3]  = {(const float*)d_in[8],  (const float*)d_in[15], (const float*)d_in[22]};
    const float* ow   = (const float*)d_in[23];
    float* ws  = (float*)d_ws;
    float* out = (float*)d_out;

    transpose_in_kernel<<<dim3(256), 256, 0, stream>>>(ipw, ws + WTIN_OFF);
    inproj_kernel<<<dim3(256, 4), 256, 0, stream>>>(x_in, ws + WTIN_OFF, ws);
    front_kernel<<<dim3(128, 4, 3), 256, 0, stream>>>(ws,
        xpw[0], xpw[1], xpw[2], dtw[0], dtw[1], dtw[2], dtb[0], dtb[1], dtb[2],
        cw[0], cb[0], cw[1], cb[1], cw[2], cb[2]);
    scan_kernel<<<dim3(256, 4, 3), 512, 0, stream>>>(ws,
        alog[0], dp[0], alog[1], dp[1], alog[2], dp[2]);
    transpose_w_kernel<<<dim3(128), 256, 0, stream>>>(ow, ws + WTOUT_OFF);
    epilogue_kernel<<<dim3(256, 4), 256, 0, stream>>>(ws, ws + WTOUT_OFF, out);
}